// Round 16
// baseline (299.179 us; speedup 1.0000x reference)
//
#include <hip/hip_runtime.h>
#include <hip/hip_fp16.h>

#define NNODE 20000
#define NE    600000
#define NES   (NE + NNODE)   // ep stride incl. self slots (used by gg, rr)
#define DF    128
#define DOUT  16
#define NBKT  160         // dst buckets
#define RNG   125         // nodes per bucket (160*125 = 20000 exact)
#define NCH   256         // partition chunks
#define CHE   2344        // edges per chunk (256*2344 >= NE)
#define P2CAP 6144        // part2 staging capacity (mean 3750 + 5 sigma + 125 self << cap)
#define SB2   128         // degree chunks per stream
#define CS2   4688        // edges per chunk (128*4688 >= NE)

typedef _Float16 f16x8 __attribute__((ext_vector_type(8)));
typedef _Float16 f16x2 __attribute__((ext_vector_type(2)));
typedef float f32x4 __attribute__((ext_vector_type(4)));

static inline int ceil_div(int a, int b) { return (a + b - 1) / b; }

// ---------------- fp32 -> fp16 conversion ----------------
struct CvtP { const float* in[2]; __half* out[2]; };
__global__ __launch_bounds__(256) void cvt_k(CvtP P) {
    int g = blockIdx.y;
    int i = blockIdx.x * 256 + threadIdx.x;
    const float4* in = (const float4*)P.in[g];
    __half2* out = (__half2*)P.out[g];
    float4 v = in[i];
    out[2 * i + 0] = __floats2half2_rn(v.x, v.y);
    out[2 * i + 1] = __floats2half2_rn(v.z, v.w);
}

// ---------------- W prep: combined, transposed, fp16 + folded bias ----------------
__global__ __launch_bounds__(256) void prepW_k(const float* __restrict__ W_conv,
                                               const float* __restrict__ b_conv,
                                               __half* __restrict__ WtH,
                                               float* __restrict__ bsum) {
    int lg = blockIdx.y;
    int l = lg >> 1, g = lg & 1;
    int ra = (g == 0) ? 0 : 1;
    int rb = (g == 0) ? 2 : 3;
    int idx = blockIdx.x * 256 + threadIdx.x;
    int col = idx >> 8, k = idx & 255;
    const float* Wa = W_conv + (size_t)(l * 4 + ra) * 128 * 128;
    const float* Wb = W_conv + (size_t)(l * 4 + rb) * 128 * 128;
    float v = (k < 128) ? Wa[k * 128 + col] : Wb[(k - 128) * 128 + col];
    WtH[((size_t)lg * 128 + col) * 256 + k] = __float2half(v);
    if (idx < 128)
        bsum[lg * 128 + idx] = 0.5f * (b_conv[(l * 4 + ra) * 128 + idx] +
                                       b_conv[(l * 4 + rb) * 128 + idx]);
}

// ---------------- bucket counts per (relation, chunk) ----------------
struct C1P { const int* col[4]; int* cnt1; };
__global__ __launch_bounds__(256) void count1_k(C1P P) {
    __shared__ int h[NBKT];
    int ch = blockIdx.x, r = blockIdx.y;
    for (int i = threadIdx.x; i < NBKT; i += 256) h[i] = 0;
    __syncthreads();
    const int* col = P.col[r];
    int e0 = ch * CHE, e1 = min(NE, e0 + CHE);
    for (int e = e0 + threadIdx.x; e < e1; e += 256) atomicAdd(&h[col[e] / RNG], 1);
    __syncthreads();
    int* out = P.cnt1 + (size_t)r * NBKT * NCH;
    for (int b = threadIdx.x; b < NBKT; b += 256) out[b * NCH + ch] = h[b];
}

// ---------------- scans: chunk offsets within bucket + bucket bases ----------------
__global__ __launch_bounds__(256) void scan1_k(int* __restrict__ cnt1, int* __restrict__ bktbase) {
    __shared__ int tot[NBKT];
    int r = blockIdx.x;
    int* base = cnt1 + (size_t)r * NBKT * NCH;
    for (int b = threadIdx.x; b < NBKT; b += 256) {
        int run = 0;
        int* pb = base + b * NCH;
        for (int ch = 0; ch < NCH; ++ch) { int v = pb[ch]; pb[ch] = run; run += v; }
        tot[b] = run;
    }
    __syncthreads();
    if (threadIdx.x == 0) {
        int run = 0;
        int* bb = bktbase + r * (NBKT + 1);
        for (int b = 0; b < NBKT; ++b) { bb[b] = run; run += tot[b]; }
        bb[NBKT] = run;
    }
}

// ---------------- part1: sort chunk by bucket in LDS, flush runs coalesced ----------------
struct P1P {
    const int* row[4]; const int* col[4]; const float* w[4];
    const int* choff;
    const int* bktbase;
    uint2* bk[4];
};
__global__ __launch_bounds__(256) void part1_k(P1P P) {
    __shared__ uint2 st[CHE];
    __shared__ int h[NBKT];
    __shared__ int hoff[NBKT];
    __shared__ int c2[NBKT];
    int ch = blockIdx.x, r = blockIdx.y;
    for (int i = threadIdx.x; i < NBKT; i += 256) { h[i] = 0; c2[i] = 0; }
    __syncthreads();
    const int* col = P.col[r];
    const int* row = P.row[r];
    const float* w = P.w[r];
    int e0 = ch * CHE, e1 = min(NE, e0 + CHE);
    for (int e = e0 + threadIdx.x; e < e1; e += 256) atomicAdd(&h[col[e] / RNG], 1);
    __syncthreads();
    if (threadIdx.x == 0) {
        int run = 0;
        for (int b = 0; b < NBKT; ++b) { hoff[b] = run; run += h[b]; }
    }
    __syncthreads();
    for (int e = e0 + threadIdx.x; e < e1; e += 256) {
        int c = col[e];
        int b = c / RNG;
        int slot = hoff[b] + atomicAdd(&c2[b], 1);
        uint2 v;
        v.x = ((unsigned)c << 15) | (unsigned)row[e];
        v.y = (unsigned)__float_as_int(w[e]);
        st[slot] = v;
    }
    __syncthreads();
    const int* choff = P.choff + (size_t)r * NBKT * NCH;
    const int* bb = P.bktbase + r * (NBKT + 1);
    uint2* bk = P.bk[r];
    for (int b = 0; b < NBKT; ++b) {
        int base = bb[b] + choff[b * NCH + ch];
        int m = h[b];
        int lo = hoff[b];
        for (int i = threadIdx.x; i < m; i += 256) bk[base + i] = st[lo + i];
    }
}

// ---------------- gg/rr dst degrees from bucketed records ----------------
struct Deg2P { const uint2* bk[2]; const int* bb[2]; float* dinv[2]; };
__global__ __launch_bounds__(256) void deg2_k(Deg2P P) {
    __shared__ float t[RNG];
    int bkt = blockIdx.x, r2 = blockIdx.y;
    for (int i = threadIdx.x; i < RNG; i += 256) t[i] = 0.f;
    __syncthreads();
    const int* bb = P.bb[r2];
    int b0 = bb[bkt], n = bb[bkt + 1] - b0;
    const uint2* bk = P.bk[r2];
    int nlo = bkt * RNG;
    for (int i = threadIdx.x; i < n; i += 256) {
        uint2 rec = bk[b0 + i];
        atomicAdd(&t[(int)(rec.x >> 15) - nlo], __int_as_float((int)rec.y));
    }
    __syncthreads();
    float* dv = P.dinv[r2];
    for (int c = threadIdx.x; c < RNG; c += 256) dv[nlo + c] = rsqrtf(t[c] + 1.0f);
}

// ---------------- 2 src-degree streams (gr row, rg row) via LDS partials ----------------
struct DegAP { const int* idx[2]; const float* wgt[2]; float* part; };
__global__ __launch_bounds__(256) void degAll_part_k(DegAP P) {
    __shared__ float t[NNODE / 2];
    int s = blockIdx.y;
    int chunk = blockIdx.x >> 1, half = blockIdx.x & 1;
    int nbase = half * (NNODE / 2);
    for (int i = threadIdx.x; i < NNODE / 2; i += 256) t[i] = 0.f;
    __syncthreads();
    const int* idx = P.idx[s];
    const float* w = P.wgt[s];
    int e0 = chunk * CS2, e1 = min(NE, e0 + CS2);
    for (int e = e0 + threadIdx.x; e < e1; e += 256) {
        int rr = idx[e] - nbase;
        if ((unsigned)rr < (unsigned)(NNODE / 2)) atomicAdd(&t[rr], w[e]);
    }
    __syncthreads();
    float* pp = P.part + ((size_t)s * SB2 + chunk) * NNODE + nbase;
    for (int i = threadIdx.x; i < NNODE / 2; i += 256) pp[i] = t[i];
}

struct DegAS { const float* part; float* dinv[2]; };
__global__ __launch_bounds__(256) void degAll_sum_k(DegAS P) {
    int s = blockIdx.y;
    int n = blockIdx.x * 256 + threadIdx.x;
    if (n >= NNODE) return;
    const float* pp = P.part + (size_t)s * SB2 * NNODE + n;
    float acc = 0.f;
    for (int c = 0; c < SB2; ++c) acc += pp[(size_t)c * NNODE];
    P.dinv[s][n] = acc > 0.f ? rsqrtf(acc) : 0.f;
}

// ---------------- part2: bucket -> CSR segment (parallel scan) ----------------
struct P2P {
    const uint2* bk[4];
    const int* bktbase;
    const float* dS[4];
    const float* dDg[4];
    int self[4];
    int* rowptr[4];
    unsigned int* ep[4];
};
__global__ __launch_bounds__(256) void part2_k(P2P P) {
    __shared__ unsigned int st[P2CAP];
    __shared__ float wsum[RNG];
    __shared__ int cnt[RNG];
    __shared__ int off[RNG + 1];
    __shared__ int cur[RNG];
    __shared__ int sc[128];
    int bkt = blockIdx.x, r = blockIdx.y;
    int selfF = P.self[r];
    const int* bb = P.bktbase + r * (NBKT + 1);
    int b0 = bb[bkt], n = bb[bkt + 1] - b0;
    for (int i = threadIdx.x; i < RNG; i += 256) { wsum[i] = 0.f; cnt[i] = 0; cur[i] = 0; }
    __syncthreads();
    const uint2* bk = P.bk[r];
    int nlo = bkt * RNG;
    for (int i = threadIdx.x; i < n; i += 256) {
        uint2 rec = bk[b0 + i];
        int cl = (int)(rec.x >> 15) - nlo;
        atomicAdd(&cnt[cl], 1);
        if (!selfF) atomicAdd(&wsum[cl], __int_as_float((int)rec.y));
    }
    __syncthreads();
    // parallel exclusive scan over RNG (=125) counts, 128-slot Hillis-Steele
    int v = 0;
    if (threadIdx.x < 128) {
        v = (threadIdx.x < RNG) ? cnt[threadIdx.x] + selfF : 0;
        sc[threadIdx.x] = v;
    }
    __syncthreads();
    for (int o = 1; o < 128; o <<= 1) {
        int add = 0;
        if (threadIdx.x < 128 && threadIdx.x >= o) add = sc[threadIdx.x - o];
        __syncthreads();
        if (threadIdx.x < 128) sc[threadIdx.x] += add;
        __syncthreads();
    }
    if (threadIdx.x < RNG) off[threadIdx.x] = sc[threadIdx.x] - v;
    if (threadIdx.x == 127) off[RNG] = sc[127];
    __syncthreads();
    int ntot = off[RNG];
    int epseg = b0 + (selfF ? nlo : 0);
    int* rp = P.rowptr[r];
    for (int c = threadIdx.x; c < RNG; c += 256) rp[nlo + c] = epseg + off[c];
    if (bkt == NBKT - 1 && threadIdx.x == 0) rp[NNODE] = epseg + ntot;
    const float* dDg = P.dDg[r];
    if (!selfF) {
        for (int c = threadIdx.x; c < RNG; c += 256) {
            float s = wsum[c];
            wsum[c] = s > 0.f ? rsqrtf(s) : 0.f;
        }
    }
    __syncthreads();
    if (selfF) {
        for (int c = threadIdx.x; c < RNG; c += 256) {
            float d = dDg[nlo + c];
            __half hh = __float2half(d * d);
            st[off[c]] = ((unsigned)(nlo + c) << 16) | *reinterpret_cast<unsigned short*>(&hh);
        }
    }
    const float* dS = P.dS[r];
    for (int i = threadIdx.x; i < n; i += 256) {
        uint2 rec = bk[b0 + i];
        int cg = (int)(rec.x >> 15);
        int cl = cg - nlo;
        int src = (int)(rec.x & 0x7fffu);
        float w = __int_as_float((int)rec.y);
        float dD = selfF ? dDg[cg] : wsum[cl];
        float nm = dS[src] * w * dD;
        int slot = off[cl] + selfF + atomicAdd(&cur[cl], 1);
        __half hh = __float2half(nm);
        st[slot] = ((unsigned)src << 16) | *reinterpret_cast<unsigned short*>(&hh);
    }
    __syncthreads();
    unsigned int* ep = P.ep[r];
    for (int i = threadIdx.x; i < ntot; i += 256) ep[epseg + i] = st[i];
}

// ---------------- pull-SpMM: quarter-wave gather, dot2 pairs (R12 proven form) ----------------
struct SpmmP {
    const __half* x[4]; const int* rowptr[4]; const unsigned int* ep[4]; __half* out[4];
};
__global__ __launch_bounds__(256) void spmm4_k(SpmmP P) {
    int b = blockIdx.x;
    int xcd = b & 7;
    int j = b >> 3;
    int r = ((xcd >> 2) << 1) + (j >= 1250 ? 1 : 0);
    int nodeblk = (xcd & 3) * 1250 + (j >= 1250 ? j - 1250 : j);
    int wid = nodeblk * 4 + (threadIdx.x >> 6);
    int lane = threadIdx.x & 63;
    int q = lane >> 4, c = lane & 15;
    const uint4* x4 = (const uint4*)P.x[r];
    const int* rp = P.rowptr[r];
    int bb = rp[wid], ee = rp[wid + 1];
    const unsigned int* ep = P.ep[r];
    float a[8];
#pragma unroll
    for (int t = 0; t < 8; ++t) a[t] = 0.f;

    auto decn = [](unsigned int v) -> float {
        unsigned short us = (unsigned short)(v & 0xffffu);
        __half h = *reinterpret_cast<__half*>(&us);
        return __half2float(h);
    };
    auto accum1 = [&](uint4 p, float n) {
        const __half2* ph = (const __half2*)&p;
#pragma unroll
        for (int t = 0; t < 4; ++t) {
            float2 f = __half22float2(ph[t]);
            a[2 * t]     = fmaf(f.x, n, a[2 * t]);
            a[2 * t + 1] = fmaf(f.y, n, a[2 * t + 1]);
        }
    };
    auto accum2 = [&](uint4 p0, uint4 p1, unsigned n01) {
        f16x2 nn = __builtin_bit_cast(f16x2, n01);
        const unsigned* u0 = (const unsigned*)&p0;
        const unsigned* u1 = (const unsigned*)&p1;
#pragma unroll
        for (int t = 0; t < 4; ++t) {
            unsigned plo = __builtin_amdgcn_perm(u1[t], u0[t], 0x05040100u);
            unsigned phi = __builtin_amdgcn_perm(u1[t], u0[t], 0x07060302u);
            a[2 * t]     = __builtin_amdgcn_fdot2(__builtin_bit_cast(f16x2, plo), nn, a[2 * t], false);
            a[2 * t + 1] = __builtin_amdgcn_fdot2(__builtin_bit_cast(f16x2, phi), nn, a[2 * t + 1], false);
        }
    };

    int i = bb + q;
    for (; i + 12 < ee; i += 16) {                // 4 edges per quarter in flight
        unsigned v0 = ep[i], v1 = ep[i + 4], v2 = ep[i + 8], v3 = ep[i + 12];
        uint4 p0 = x4[(size_t)(v0 >> 16) * 16 + c];
        uint4 p1 = x4[(size_t)(v1 >> 16) * 16 + c];
        uint4 p2 = x4[(size_t)(v2 >> 16) * 16 + c];
        uint4 p3 = x4[(size_t)(v3 >> 16) * 16 + c];
        accum2(p0, p1, __builtin_amdgcn_perm(v1, v0, 0x05040100u));
        accum2(p2, p3, __builtin_amdgcn_perm(v3, v2, 0x05040100u));
    }
    for (; i + 4 < ee; i += 8) {                  // 2 edges
        unsigned v0 = ep[i], v1 = ep[i + 4];
        uint4 p0 = x4[(size_t)(v0 >> 16) * 16 + c];
        uint4 p1 = x4[(size_t)(v1 >> 16) * 16 + c];
        accum2(p0, p1, __builtin_amdgcn_perm(v1, v0, 0x05040100u));
    }
    if (i < ee) {
        unsigned v0 = ep[i];
        uint4 p0 = x4[(size_t)(v0 >> 16) * 16 + c];
        accum1(p0, decn(v0));
    }
#pragma unroll
    for (int t = 0; t < 8; ++t) {
        a[t] += __shfl_xor(a[t], 16, 64);
        a[t] += __shfl_xor(a[t], 32, 64);
    }
    if (q == 0) {
        __half2 h[4];
#pragma unroll
        for (int t = 0; t < 4; ++t) h[t] = __floats2half2_rn(a[2 * t], a[2 * t + 1]);
        ((uint4*)P.out[r])[(size_t)wid * 16 + c] = *(uint4*)h;
    }
}

// ---------------- MFMA gemm2 ----------------
struct Gemm2P {
    const __half* A1[2]; const __half* A2[2];
    const __half* Wt[2];
    const float* bs[2];
    __half* out[2];
};
__global__ __launch_bounds__(256) void gemm2_k(Gemm2P P) {
    __shared__ __half sW[128 * 136];
    int g = blockIdx.y;
    int w = threadIdx.x >> 6, l = threadIdx.x & 63;
    int r0 = blockIdx.x * 64 + w * 16;
    int lm = l & 15, lh = l >> 4;
    f32x4 acc[8];
    f32x4 zero = {0.f, 0.f, 0.f, 0.f};
#pragma unroll
    for (int n = 0; n < 8; ++n) acc[n] = zero;
    const __half* As[2] = { P.A1[g], P.A2[g] };
    const uint4* wg = (const uint4*)P.Wt[g];
    int arow = r0 + lm;
    bool rok = arow < NNODE;
    for (int s = 0; s < 2; ++s) {
        __syncthreads();
        for (int u = threadIdx.x; u < 2048; u += 256) {
            int col = u >> 4, kb8 = u & 15;
            uint4 vv = wg[col * 32 + s * 16 + kb8];
            *(uint4*)&sW[col * 136 + kb8 * 8] = vv;
        }
        __syncthreads();
        const uint4* a4 = (const uint4*)As[s];
#pragma unroll
        for (int kk = 0; kk < 4; ++kk) {
            uint4 av = make_uint4(0, 0, 0, 0);
            if (rok) av = a4[(size_t)arow * 16 + kk * 4 + lh];
            f16x8 af = *(f16x8*)&av;
#pragma unroll
            for (int n = 0; n < 8; ++n) {
                uint4 bv = *(uint4*)&sW[(n * 16 + lm) * 136 + kk * 32 + lh * 8];
                f16x8 bf = *(f16x8*)&bv;
                acc[n] = __builtin_amdgcn_mfma_f32_16x16x32_f16(af, bf, acc[n], 0, 0, 0);
            }
        }
    }
    __half* out = P.out[g];
    const float* bs = P.bs[g];
#pragma unroll
    for (int n = 0; n < 8; ++n) {
        int colg = n * 16 + lm;
        float bb = bs[colg];
#pragma unroll
        for (int qq = 0; qq < 4; ++qq) {
            int rowg = r0 + lh * 4 + qq;
            if (rowg < NNODE) {
                float v = fmaf(acc[n][qq], 0.5f, bb);
                out[(size_t)rowg * 128 + colg] = __float2half(v > 0.f ? v : 0.f);
            }
        }
    }
}

struct Lin16P { const __half* x[2]; const float* W[2]; const float* b[2]; float* out[2]; };
__global__ __launch_bounds__(256) void lin16_k(Lin16P P) {
    int g = blockIdx.y;
    int idx = blockIdx.x * 256 + threadIdx.x;
    int row = idx >> 4, c = idx & 15;
    if (row >= NNODE) return;
    const __half* xr = P.x[g] + (size_t)row * 128;
    const float* W = P.W[g];
    float acc = P.b[g][c];
    for (int k = 0; k < 128; ++k) acc += __half2float(xr[k]) * W[k * 16 + c];
    P.out[g][(size_t)row * 16 + c] = acc;
}

extern "C" void kernel_launch(void* const* d_in, const int* in_sizes, int n_in,
                              void* d_out, int out_size, void* d_ws, size_t ws_size,
                              hipStream_t stream) {
    (void)in_sizes; (void)n_in; (void)out_size; (void)ws_size;

    const float* x_gen  = (const float*)d_in[0];
    const float* x_rain = (const float*)d_in[1];
    const int* ei[4] = {(const int*)d_in[2], (const int*)d_in[3], (const int*)d_in[4], (const int*)d_in[5]};
    const float* w[4] = {(const float*)d_in[6], (const float*)d_in[7], (const float*)d_in[8], (const float*)d_in[9]};
    const float* W_conv = (const float*)d_in[10];
    const float* b_conv = (const float*)d_in[11];
    const float* W_lg = (const float*)d_in[12];
    const float* b_lg = (const float*)d_in[13];
    const float* W_lr = (const float*)d_in[14];
    const float* b_lr = (const float*)d_in[15];

    float* out_gen  = (float*)d_out;
    float* out_rain = out_gen + (size_t)NNODE * DOUT;

    char* p = (char*)d_ws;
    auto alloc = [&](size_t bytes) -> void* {
        void* r = (void*)p;
        p += (bytes + 255) & ~(size_t)255;
        return r;
    };

    float* deg = (float*)alloc(4 * (size_t)NNODE * sizeof(float));
    float* dinv_gg   = deg + 0 * NNODE;
    float* dinv_rr   = deg + 1 * NNODE;
    float* dinv_gr_s = deg + 2 * NNODE;
    float* dinv_rg_s = deg + 3 * NNODE;

    int* rowptr_all = (int*)alloc(4 * (size_t)(NNODE + 1) * sizeof(int));
    int* cnt1       = (int*)alloc(4 * (size_t)NBKT * NCH * sizeof(int));
    int* bktbase    = (int*)alloc(4 * (size_t)(NBKT + 1) * sizeof(int));

    size_t epack_bytes = 4 * (size_t)NES * sizeof(unsigned int);
    size_t part_bytes  = 2 * (size_t)SB2 * NNODE * sizeof(float);
    unsigned int* epack_all = (unsigned int*)alloc(epack_bytes > part_bytes ? epack_bytes : part_bytes);
    float* part_all = (float*)epack_all;

    __half* agg_all = (__half*)alloc(4 * (size_t)NNODE * DF * sizeof(__half));
    __half* aggh_gg = agg_all + 0 * (size_t)NNODE * DF;
    __half* aggh_gr = agg_all + 1 * (size_t)NNODE * DF;
    __half* aggh_rg = agg_all + 2 * (size_t)NNODE * DF;
    __half* aggh_rr = agg_all + 3 * (size_t)NNODE * DF;
    uint2* bk_all = (uint2*)agg_all;

    __half* xh_gen  = (__half*)alloc((size_t)NNODE * DF * sizeof(__half));
    __half* xh_rain = (__half*)alloc((size_t)NNODE * DF * sizeof(__half));
    __half* WtH  = (__half*)alloc(4 * (size_t)128 * 256 * sizeof(__half));
    float*  bsum = (float*)alloc(4 * 128 * sizeof(float));

    int* rowptr[4]; unsigned int* ep[4]; uint2* bk[4];
    for (int r = 0; r < 4; ++r) {
        rowptr[r] = rowptr_all + (size_t)r * (NNODE + 1);
        ep[r]     = epack_all + (size_t)r * NES;
        bk[r]     = bk_all + (size_t)r * NE;
    }

    const int* rows_[4] = {ei[0], ei[1], ei[2], ei[3]};
    const int* cols_[4] = {ei[0] + NE, ei[1] + NE, ei[2] + NE, ei[3] + NE};

    prepW_k<<<dim3(128, 4), 256, 0, stream>>>(W_conv, b_conv, WtH, bsum);

    C1P C1;
    for (int r = 0; r < 4; ++r) C1.col[r] = cols_[r];
    C1.cnt1 = cnt1;
    count1_k<<<dim3(NCH, 4), 256, 0, stream>>>(C1);
    scan1_k<<<4, 256, 0, stream>>>(cnt1, bktbase);

    P1P P1;
    for (int r = 0; r < 4; ++r) {
        P1.row[r] = rows_[r]; P1.col[r] = cols_[r]; P1.w[r] = w[r]; P1.bk[r] = bk[r];
    }
    P1.choff = cnt1;
    P1.bktbase = bktbase;
    part1_k<<<dim3(NCH, 4), 256, 0, stream>>>(P1);

    Deg2P D2;
    D2.bk[0] = bk[0]; D2.bb[0] = bktbase + 0 * (NBKT + 1); D2.dinv[0] = dinv_gg;
    D2.bk[1] = bk[3]; D2.bb[1] = bktbase + 3 * (NBKT + 1); D2.dinv[1] = dinv_rr;
    deg2_k<<<dim3(NBKT, 2), 256, 0, stream>>>(D2);

    DegAP DA;
    DA.idx[0] = rows_[1]; DA.wgt[0] = w[1];
    DA.idx[1] = rows_[2]; DA.wgt[1] = w[2];
    DA.part = part_all;
    degAll_part_k<<<dim3(SB2 * 2, 2), 256, 0, stream>>>(DA);

    DegAS DAS;
    DAS.part = part_all;
    DAS.dinv[0] = dinv_gr_s;
    DAS.dinv[1] = dinv_rg_s;
    degAll_sum_k<<<dim3(ceil_div(NNODE, 256), 2), 256, 0, stream>>>(DAS);

    P2P P2;
    for (int r = 0; r < 4; ++r) { P2.bk[r] = bk[r]; P2.rowptr[r] = rowptr[r]; P2.ep[r] = ep[r]; }
    P2.bktbase = bktbase;
    P2.dS[0] = dinv_gg;   P2.dDg[0] = dinv_gg;   P2.self[0] = 1;
    P2.dS[1] = dinv_gr_s; P2.dDg[1] = nullptr;   P2.self[1] = 0;
    P2.dS[2] = dinv_rg_s; P2.dDg[2] = nullptr;   P2.self[2] = 0;
    P2.dS[3] = dinv_rr;   P2.dDg[3] = dinv_rr;   P2.self[3] = 1;
    part2_k<<<dim3(NBKT, 4), 256, 0, stream>>>(P2);

    CvtP CV;
    CV.in[0] = x_gen;  CV.out[0] = xh_gen;
    CV.in[1] = x_rain; CV.out[1] = xh_rain;
    cvt_k<<<dim3(NNODE * DF / 4 / 256, 2), 256, 0, stream>>>(CV);

    for (int l = 0; l < 2; ++l) {
        SpmmP SP;
        for (int r = 0; r < 4; ++r) { SP.rowptr[r] = rowptr[r]; SP.ep[r] = ep[r]; }
        SP.x[0] = xh_gen; SP.x[1] = xh_gen; SP.x[2] = xh_rain; SP.x[3] = xh_rain;
        SP.out[0] = aggh_gg; SP.out[1] = aggh_gr; SP.out[2] = aggh_rg; SP.out[3] = aggh_rr;
        spmm4_k<<<20000, 256, 0, stream>>>(SP);

        Gemm2P GP;
        GP.A1[0] = aggh_gg; GP.A2[0] = aggh_rg;
        GP.A1[1] = aggh_gr; GP.A2[1] = aggh_rr;
        GP.Wt[0] = WtH + (size_t)(l * 2 + 0) * 128 * 256;
        GP.Wt[1] = WtH + (size_t)(l * 2 + 1) * 128 * 256;
        GP.bs[0] = bsum + (l * 2 + 0) * 128;
        GP.bs[1] = bsum + (l * 2 + 1) * 128;
        GP.out[0] = xh_gen;
        GP.out[1] = xh_rain;
        gemm2_k<<<dim3(ceil_div(NNODE, 64), 2), 256, 0, stream>>>(GP);
    }

    Lin16P LP;
    LP.x[0] = xh_gen;  LP.W[0] = W_lg; LP.b[0] = b_lg; LP.out[0] = out_gen;
    LP.x[1] = xh_rain; LP.W[1] = W_lr; LP.b[1] = b_lr; LP.out[1] = out_rain;
    lin16_k<<<dim3(ceil_div(NNODE * DOUT, 256), 2), 256, 0, stream>>>(LP);
}

// Round 17
// 269.399 us; speedup vs baseline: 1.1105x; 1.1105x over previous
//
#include <hip/hip_runtime.h>
#include <hip/hip_fp16.h>

#define NNODE 20000
#define NE    600000
#define NES   (NE + NNODE)   // ep stride incl. self slots (used by gg, rr)
#define DF    128
#define DOUT  16
#define NBKT  80          // dst buckets
#define RNG   250         // nodes per bucket (80*250 = 20000 exact)
#define NCH   128         // partition chunks
#define CHE   4688        // edges per chunk (128*4688 >= NE)
#define P2CAP 12288       // part2 staging capacity
#define SB2   64          // degree chunks per stream
#define CS2   (NE/SB2)    // 9375

typedef _Float16 f16x8 __attribute__((ext_vector_type(8)));
typedef _Float16 f16x2 __attribute__((ext_vector_type(2)));
typedef float f32x4 __attribute__((ext_vector_type(4)));

static inline int ceil_div(int a, int b) { return (a + b - 1) / b; }

// ---------------- fp32 -> fp16 conversion ----------------
struct CvtP { const float* in[2]; __half* out[2]; };
__global__ __launch_bounds__(256) void cvt_k(CvtP P) {
    int g = blockIdx.y;
    int i = blockIdx.x * 256 + threadIdx.x;
    const float4* in = (const float4*)P.in[g];
    __half2* out = (__half2*)P.out[g];
    float4 v = in[i];
    out[2 * i + 0] = __floats2half2_rn(v.x, v.y);
    out[2 * i + 1] = __floats2half2_rn(v.z, v.w);
}

// ---------------- W prep: combined, transposed, fp16 + folded bias ----------------
__global__ __launch_bounds__(256) void prepW_k(const float* __restrict__ W_conv,
                                               const float* __restrict__ b_conv,
                                               __half* __restrict__ WtH,
                                               float* __restrict__ bsum) {
    int lg = blockIdx.y;
    int l = lg >> 1, g = lg & 1;
    int ra = (g == 0) ? 0 : 1;
    int rb = (g == 0) ? 2 : 3;
    int idx = blockIdx.x * 256 + threadIdx.x;
    int col = idx >> 8, k = idx & 255;
    const float* Wa = W_conv + (size_t)(l * 4 + ra) * 128 * 128;
    const float* Wb = W_conv + (size_t)(l * 4 + rb) * 128 * 128;
    float v = (k < 128) ? Wa[k * 128 + col] : Wb[(k - 128) * 128 + col];
    WtH[((size_t)lg * 128 + col) * 256 + k] = __float2half(v);
    if (idx < 128)
        bsum[lg * 128 + idx] = 0.5f * (b_conv[(l * 4 + ra) * 128 + idx] +
                                       b_conv[(l * 4 + rb) * 128 + idx]);
}

// ---------------- bucket counts per (relation, chunk) ----------------
struct C1P { const int* col[4]; int* cnt1; };
__global__ __launch_bounds__(256) void count1_k(C1P P) {
    __shared__ int h[NBKT];
    int ch = blockIdx.x, r = blockIdx.y;
    for (int i = threadIdx.x; i < NBKT; i += 256) h[i] = 0;
    __syncthreads();
    const int* col = P.col[r];
    int e0 = ch * CHE, e1 = min(NE, e0 + CHE);
    for (int e = e0 + threadIdx.x; e < e1; e += 256) atomicAdd(&h[col[e] / RNG], 1);
    __syncthreads();
    int* out = P.cnt1 + (size_t)r * NBKT * NCH;
    for (int b = threadIdx.x; b < NBKT; b += 256) out[b * NCH + ch] = h[b];
}

// ---------------- scans: chunk offsets within bucket + bucket bases ----------------
__global__ __launch_bounds__(128) void scan1_k(int* __restrict__ cnt1, int* __restrict__ bktbase) {
    __shared__ int tot[NBKT];
    int r = blockIdx.x;
    int* base = cnt1 + (size_t)r * NBKT * NCH;
    for (int b = threadIdx.x; b < NBKT; b += 128) {
        int run = 0;
        int* pb = base + b * NCH;
        for (int ch = 0; ch < NCH; ++ch) { int v = pb[ch]; pb[ch] = run; run += v; }
        tot[b] = run;
    }
    __syncthreads();
    if (threadIdx.x == 0) {
        int run = 0;
        int* bb = bktbase + r * (NBKT + 1);
        for (int b = 0; b < NBKT; ++b) { bb[b] = run; run += tot[b]; }
        bb[NBKT] = run;
    }
}

// ---------------- part1: sort chunk by bucket in LDS, flush runs coalesced ----------------
struct P1P {
    const int* row[4]; const int* col[4]; const float* w[4];
    const int* choff;
    const int* bktbase;
    uint2* bk[4];
};
__global__ __launch_bounds__(256) void part1_k(P1P P) {
    __shared__ uint2 st[CHE];
    __shared__ int h[NBKT];
    __shared__ int hoff[NBKT];
    __shared__ int c2[NBKT];
    int ch = blockIdx.x, r = blockIdx.y;
    for (int i = threadIdx.x; i < NBKT; i += 256) { h[i] = 0; c2[i] = 0; }
    __syncthreads();
    const int* col = P.col[r];
    const int* row = P.row[r];
    const float* w = P.w[r];
    int e0 = ch * CHE, e1 = min(NE, e0 + CHE);
    for (int e = e0 + threadIdx.x; e < e1; e += 256) atomicAdd(&h[col[e] / RNG], 1);
    __syncthreads();
    if (threadIdx.x == 0) {
        int run = 0;
        for (int b = 0; b < NBKT; ++b) { hoff[b] = run; run += h[b]; }
    }
    __syncthreads();
    for (int e = e0 + threadIdx.x; e < e1; e += 256) {
        int c = col[e];
        int b = c / RNG;
        int slot = hoff[b] + atomicAdd(&c2[b], 1);
        uint2 v;
        v.x = ((unsigned)c << 15) | (unsigned)row[e];
        v.y = (unsigned)__float_as_int(w[e]);
        st[slot] = v;
    }
    __syncthreads();
    const int* choff = P.choff + (size_t)r * NBKT * NCH;
    const int* bb = P.bktbase + r * (NBKT + 1);
    uint2* bk = P.bk[r];
    for (int b = 0; b < NBKT; ++b) {
        int base = bb[b] + choff[b * NCH + ch];
        int m = h[b];
        int lo = hoff[b];
        for (int i = threadIdx.x; i < m; i += 256) bk[base + i] = st[lo + i];
    }
}

// ---------------- gg/rr dst degrees from bucketed records ----------------
struct Deg2P { const uint2* bk[2]; const int* bb[2]; float* dinv[2]; };
__global__ __launch_bounds__(256) void deg2_k(Deg2P P) {
    __shared__ float t[RNG];
    int bkt = blockIdx.x, r2 = blockIdx.y;
    for (int i = threadIdx.x; i < RNG; i += 256) t[i] = 0.f;
    __syncthreads();
    const int* bb = P.bb[r2];
    int b0 = bb[bkt], n = bb[bkt + 1] - b0;
    const uint2* bk = P.bk[r2];
    int nlo = bkt * RNG;
    for (int i = threadIdx.x; i < n; i += 256) {
        uint2 rec = bk[b0 + i];
        atomicAdd(&t[(int)(rec.x >> 15) - nlo], __int_as_float((int)rec.y));
    }
    __syncthreads();
    float* dv = P.dinv[r2];
    for (int c = threadIdx.x; c < RNG; c += 256) dv[nlo + c] = rsqrtf(t[c] + 1.0f);
}

// ---------------- 2 src-degree streams (gr row, rg row) via LDS partials ----------------
struct DegAP { const int* idx[2]; const float* wgt[2]; float* part; };
__global__ __launch_bounds__(256) void degAll_part_k(DegAP P) {
    __shared__ float t[NNODE / 2];
    int s = blockIdx.y;
    int chunk = blockIdx.x >> 1, half = blockIdx.x & 1;
    int nbase = half * (NNODE / 2);
    for (int i = threadIdx.x; i < NNODE / 2; i += 256) t[i] = 0.f;
    __syncthreads();
    const int* idx = P.idx[s];
    const float* w = P.wgt[s];
    int e0 = chunk * CS2, e1 = min(NE, e0 + CS2);
    for (int e = e0 + threadIdx.x; e < e1; e += 256) {
        int rr = idx[e] - nbase;
        if ((unsigned)rr < (unsigned)(NNODE / 2)) atomicAdd(&t[rr], w[e]);
    }
    __syncthreads();
    float* pp = P.part + ((size_t)s * SB2 + chunk) * NNODE + nbase;
    for (int i = threadIdx.x; i < NNODE / 2; i += 256) pp[i] = t[i];
}

struct DegAS { const float* part; float* dinv[2]; };
__global__ __launch_bounds__(256) void degAll_sum_k(DegAS P) {
    int s = blockIdx.y;
    int n = blockIdx.x * 256 + threadIdx.x;
    if (n >= NNODE) return;
    const float* pp = P.part + (size_t)s * SB2 * NNODE + n;
    float acc = 0.f;
    for (int c = 0; c < SB2; ++c) acc += pp[(size_t)c * NNODE];
    P.dinv[s][n] = acc > 0.f ? rsqrtf(acc) : 0.f;
}

// ---------------- part2: bucket -> CSR segment (parallel 256-slot scan) ----------------
struct P2P {
    const uint2* bk[4];
    const int* bktbase;
    const float* dS[4];
    const float* dDg[4];
    int self[4];
    int* rowptr[4];
    unsigned int* ep[4];
};
__global__ __launch_bounds__(256) void part2_k(P2P P) {
    __shared__ unsigned int st[P2CAP];
    __shared__ float wsum[RNG];
    __shared__ int cnt[RNG];
    __shared__ int off[RNG + 1];
    __shared__ int cur[RNG];
    __shared__ int sc[256];
    int bkt = blockIdx.x, r = blockIdx.y;
    int selfF = P.self[r];
    const int* bb = P.bktbase + r * (NBKT + 1);
    int b0 = bb[bkt], n = bb[bkt + 1] - b0;
    for (int i = threadIdx.x; i < RNG; i += 256) { wsum[i] = 0.f; cnt[i] = 0; cur[i] = 0; }
    __syncthreads();
    const uint2* bk = P.bk[r];
    int nlo = bkt * RNG;
    for (int i = threadIdx.x; i < n; i += 256) {
        uint2 rec = bk[b0 + i];
        int cl = (int)(rec.x >> 15) - nlo;
        atomicAdd(&cnt[cl], 1);
        if (!selfF) atomicAdd(&wsum[cl], __int_as_float((int)rec.y));
    }
    __syncthreads();
    // parallel exclusive scan over RNG (=250) counts, 256-slot Hillis-Steele
    int v = (threadIdx.x < RNG) ? cnt[threadIdx.x] + selfF : 0;
    sc[threadIdx.x] = v;
    __syncthreads();
    for (int o = 1; o < 256; o <<= 1) {
        int add = (threadIdx.x >= o) ? sc[threadIdx.x - o] : 0;
        __syncthreads();
        sc[threadIdx.x] += add;
        __syncthreads();
    }
    if (threadIdx.x < RNG) off[threadIdx.x] = sc[threadIdx.x] - v;
    if (threadIdx.x == 255) off[RNG] = sc[255];
    __syncthreads();
    int ntot = off[RNG];
    int epseg = b0 + (selfF ? nlo : 0);
    int* rp = P.rowptr[r];
    for (int c = threadIdx.x; c < RNG; c += 256) rp[nlo + c] = epseg + off[c];
    if (bkt == NBKT - 1 && threadIdx.x == 0) rp[NNODE] = epseg + ntot;
    const float* dDg = P.dDg[r];
    if (!selfF) {
        for (int c = threadIdx.x; c < RNG; c += 256) {
            float s = wsum[c];
            wsum[c] = s > 0.f ? rsqrtf(s) : 0.f;
        }
    }
    __syncthreads();
    if (selfF) {
        for (int c = threadIdx.x; c < RNG; c += 256) {
            float d = dDg[nlo + c];
            __half hh = __float2half(d * d);
            st[off[c]] = ((unsigned)(nlo + c) << 16) | *reinterpret_cast<unsigned short*>(&hh);
        }
    }
    const float* dS = P.dS[r];
    for (int i = threadIdx.x; i < n; i += 256) {
        uint2 rec = bk[b0 + i];
        int cg = (int)(rec.x >> 15);
        int cl = cg - nlo;
        int src = (int)(rec.x & 0x7fffu);
        float w = __int_as_float((int)rec.y);
        float dD = selfF ? dDg[cg] : wsum[cl];
        float nm = dS[src] * w * dD;
        int slot = off[cl] + selfF + atomicAdd(&cur[cl], 1);
        __half hh = __float2half(nm);
        st[slot] = ((unsigned)src << 16) | *reinterpret_cast<unsigned short*>(&hh);
    }
    __syncthreads();
    unsigned int* ep = P.ep[r];
    for (int i = threadIdx.x; i < ntot; i += 256) ep[epseg + i] = st[i];
}

// ---------------- pull-SpMM: quarter-wave gather, dot2 pairs (R12 proven form) ----------------
struct SpmmP {
    const __half* x[4]; const int* rowptr[4]; const unsigned int* ep[4]; __half* out[4];
};
__global__ __launch_bounds__(256) void spmm4_k(SpmmP P) {
    int b = blockIdx.x;
    int xcd = b & 7;
    int j = b >> 3;
    int r = ((xcd >> 2) << 1) + (j >= 1250 ? 1 : 0);
    int nodeblk = (xcd & 3) * 1250 + (j >= 1250 ? j - 1250 : j);
    int wid = nodeblk * 4 + (threadIdx.x >> 6);
    int lane = threadIdx.x & 63;
    int q = lane >> 4, c = lane & 15;
    const uint4* x4 = (const uint4*)P.x[r];
    const int* rp = P.rowptr[r];
    int bb = rp[wid], ee = rp[wid + 1];
    const unsigned int* ep = P.ep[r];
    float a[8];
#pragma unroll
    for (int t = 0; t < 8; ++t) a[t] = 0.f;

    auto decn = [](unsigned int v) -> float {
        unsigned short us = (unsigned short)(v & 0xffffu);
        __half h = *reinterpret_cast<__half*>(&us);
        return __half2float(h);
    };
    auto accum1 = [&](uint4 p, float n) {
        const __half2* ph = (const __half2*)&p;
#pragma unroll
        for (int t = 0; t < 4; ++t) {
            float2 f = __half22float2(ph[t]);
            a[2 * t]     = fmaf(f.x, n, a[2 * t]);
            a[2 * t + 1] = fmaf(f.y, n, a[2 * t + 1]);
        }
    };
    auto accum2 = [&](uint4 p0, uint4 p1, unsigned n01) {
        f16x2 nn = __builtin_bit_cast(f16x2, n01);
        const unsigned* u0 = (const unsigned*)&p0;
        const unsigned* u1 = (const unsigned*)&p1;
#pragma unroll
        for (int t = 0; t < 4; ++t) {
            unsigned plo = __builtin_amdgcn_perm(u1[t], u0[t], 0x05040100u);
            unsigned phi = __builtin_amdgcn_perm(u1[t], u0[t], 0x07060302u);
            a[2 * t]     = __builtin_amdgcn_fdot2(__builtin_bit_cast(f16x2, plo), nn, a[2 * t], false);
            a[2 * t + 1] = __builtin_amdgcn_fdot2(__builtin_bit_cast(f16x2, phi), nn, a[2 * t + 1], false);
        }
    };

    int i = bb + q;
    for (; i + 12 < ee; i += 16) {                // 4 edges per quarter in flight
        unsigned v0 = ep[i], v1 = ep[i + 4], v2 = ep[i + 8], v3 = ep[i + 12];
        uint4 p0 = x4[(size_t)(v0 >> 16) * 16 + c];
        uint4 p1 = x4[(size_t)(v1 >> 16) * 16 + c];
        uint4 p2 = x4[(size_t)(v2 >> 16) * 16 + c];
        uint4 p3 = x4[(size_t)(v3 >> 16) * 16 + c];
        accum2(p0, p1, __builtin_amdgcn_perm(v1, v0, 0x05040100u));
        accum2(p2, p3, __builtin_amdgcn_perm(v3, v2, 0x05040100u));
    }
    for (; i + 4 < ee; i += 8) {                  // 2 edges
        unsigned v0 = ep[i], v1 = ep[i + 4];
        uint4 p0 = x4[(size_t)(v0 >> 16) * 16 + c];
        uint4 p1 = x4[(size_t)(v1 >> 16) * 16 + c];
        accum2(p0, p1, __builtin_amdgcn_perm(v1, v0, 0x05040100u));
    }
    if (i < ee) {
        unsigned v0 = ep[i];
        uint4 p0 = x4[(size_t)(v0 >> 16) * 16 + c];
        accum1(p0, decn(v0));
    }
#pragma unroll
    for (int t = 0; t < 8; ++t) {
        a[t] += __shfl_xor(a[t], 16, 64);
        a[t] += __shfl_xor(a[t], 32, 64);
    }
    if (q == 0) {
        __half2 h[4];
#pragma unroll
        for (int t = 0; t < 4; ++t) h[t] = __floats2half2_rn(a[2 * t], a[2 * t + 1]);
        ((uint4*)P.out[r])[(size_t)wid * 16 + c] = *(uint4*)h;
    }
}

// ---------------- MFMA gemm2 ----------------
struct Gemm2P {
    const __half* A1[2]; const __half* A2[2];
    const __half* Wt[2];
    const float* bs[2];
    __half* out[2];
};
__global__ __launch_bounds__(256) void gemm2_k(Gemm2P P) {
    __shared__ __half sW[128 * 136];
    int g = blockIdx.y;
    int w = threadIdx.x >> 6, l = threadIdx.x & 63;
    int r0 = blockIdx.x * 64 + w * 16;
    int lm = l & 15, lh = l >> 4;
    f32x4 acc[8];
    f32x4 zero = {0.f, 0.f, 0.f, 0.f};
#pragma unroll
    for (int n = 0; n < 8; ++n) acc[n] = zero;
    const __half* As[2] = { P.A1[g], P.A2[g] };
    const uint4* wg = (const uint4*)P.Wt[g];
    int arow = r0 + lm;
    bool rok = arow < NNODE;
    for (int s = 0; s < 2; ++s) {
        __syncthreads();
        for (int u = threadIdx.x; u < 2048; u += 256) {
            int col = u >> 4, kb8 = u & 15;
            uint4 vv = wg[col * 32 + s * 16 + kb8];
            *(uint4*)&sW[col * 136 + kb8 * 8] = vv;
        }
        __syncthreads();
        const uint4* a4 = (const uint4*)As[s];
#pragma unroll
        for (int kk = 0; kk < 4; ++kk) {
            uint4 av = make_uint4(0, 0, 0, 0);
            if (rok) av = a4[(size_t)arow * 16 + kk * 4 + lh];
            f16x8 af = *(f16x8*)&av;
#pragma unroll
            for (int n = 0; n < 8; ++n) {
                uint4 bv = *(uint4*)&sW[(n * 16 + lm) * 136 + kk * 32 + lh * 8];
                f16x8 bf = *(f16x8*)&bv;
                acc[n] = __builtin_amdgcn_mfma_f32_16x16x32_f16(af, bf, acc[n], 0, 0, 0);
            }
        }
    }
    __half* out = P.out[g];
    const float* bs = P.bs[g];
#pragma unroll
    for (int n = 0; n < 8; ++n) {
        int colg = n * 16 + lm;
        float bb = bs[colg];
#pragma unroll
        for (int qq = 0; qq < 4; ++qq) {
            int rowg = r0 + lh * 4 + qq;
            if (rowg < NNODE) {
                float v = fmaf(acc[n][qq], 0.5f, bb);
                out[(size_t)rowg * 128 + colg] = __float2half(v > 0.f ? v : 0.f);
            }
        }
    }
}

struct Lin16P { const __half* x[2]; const float* W[2]; const float* b[2]; float* out[2]; };
__global__ __launch_bounds__(256) void lin16_k(Lin16P P) {
    int g = blockIdx.y;
    int idx = blockIdx.x * 256 + threadIdx.x;
    int row = idx >> 4, c = idx & 15;
    if (row >= NNODE) return;
    const __half* xr = P.x[g] + (size_t)row * 128;
    const float* W = P.W[g];
    float acc = P.b[g][c];
    for (int k = 0; k < 128; ++k) acc += __half2float(xr[k]) * W[k * 16 + c];
    P.out[g][(size_t)row * 16 + c] = acc;
}

extern "C" void kernel_launch(void* const* d_in, const int* in_sizes, int n_in,
                              void* d_out, int out_size, void* d_ws, size_t ws_size,
                              hipStream_t stream) {
    (void)in_sizes; (void)n_in; (void)out_size; (void)ws_size;

    const float* x_gen  = (const float*)d_in[0];
    const float* x_rain = (const float*)d_in[1];
    const int* ei[4] = {(const int*)d_in[2], (const int*)d_in[3], (const int*)d_in[4], (const int*)d_in[5]};
    const float* w[4] = {(const float*)d_in[6], (const float*)d_in[7], (const float*)d_in[8], (const float*)d_in[9]};
    const float* W_conv = (const float*)d_in[10];
    const float* b_conv = (const float*)d_in[11];
    const float* W_lg = (const float*)d_in[12];
    const float* b_lg = (const float*)d_in[13];
    const float* W_lr = (const float*)d_in[14];
    const float* b_lr = (const float*)d_in[15];

    float* out_gen  = (float*)d_out;
    float* out_rain = out_gen + (size_t)NNODE * DOUT;

    char* p = (char*)d_ws;
    auto alloc = [&](size_t bytes) -> void* {
        void* r = (void*)p;
        p += (bytes + 255) & ~(size_t)255;
        return r;
    };

    float* deg = (float*)alloc(4 * (size_t)NNODE * sizeof(float));
    float* dinv_gg   = deg + 0 * NNODE;
    float* dinv_rr   = deg + 1 * NNODE;
    float* dinv_gr_s = deg + 2 * NNODE;
    float* dinv_rg_s = deg + 3 * NNODE;

    int* rowptr_all = (int*)alloc(4 * (size_t)(NNODE + 1) * sizeof(int));
    int* cnt1       = (int*)alloc(4 * (size_t)NBKT * NCH * sizeof(int));
    int* bktbase    = (int*)alloc(4 * (size_t)(NBKT + 1) * sizeof(int));

    size_t epack_bytes = 4 * (size_t)NES * sizeof(unsigned int);
    size_t part_bytes  = 2 * (size_t)SB2 * NNODE * sizeof(float);
    unsigned int* epack_all = (unsigned int*)alloc(epack_bytes > part_bytes ? epack_bytes : part_bytes);
    float* part_all = (float*)epack_all;

    __half* agg_all = (__half*)alloc(4 * (size_t)NNODE * DF * sizeof(__half));
    __half* aggh_gg = agg_all + 0 * (size_t)NNODE * DF;
    __half* aggh_gr = agg_all + 1 * (size_t)NNODE * DF;
    __half* aggh_rg = agg_all + 2 * (size_t)NNODE * DF;
    __half* aggh_rr = agg_all + 3 * (size_t)NNODE * DF;
    uint2* bk_all = (uint2*)agg_all;

    __half* xh_gen  = (__half*)alloc((size_t)NNODE * DF * sizeof(__half));
    __half* xh_rain = (__half*)alloc((size_t)NNODE * DF * sizeof(__half));
    __half* WtH  = (__half*)alloc(4 * (size_t)128 * 256 * sizeof(__half));
    float*  bsum = (float*)alloc(4 * 128 * sizeof(float));

    int* rowptr[4]; unsigned int* ep[4]; uint2* bk[4];
    for (int r = 0; r < 4; ++r) {
        rowptr[r] = rowptr_all + (size_t)r * (NNODE + 1);
        ep[r]     = epack_all + (size_t)r * NES;
        bk[r]     = bk_all + (size_t)r * NE;
    }

    const int* rows_[4] = {ei[0], ei[1], ei[2], ei[3]};
    const int* cols_[4] = {ei[0] + NE, ei[1] + NE, ei[2] + NE, ei[3] + NE};

    prepW_k<<<dim3(128, 4), 256, 0, stream>>>(W_conv, b_conv, WtH, bsum);

    C1P C1;
    for (int r = 0; r < 4; ++r) C1.col[r] = cols_[r];
    C1.cnt1 = cnt1;
    count1_k<<<dim3(NCH, 4), 256, 0, stream>>>(C1);
    scan1_k<<<4, 128, 0, stream>>>(cnt1, bktbase);

    P1P P1;
    for (int r = 0; r < 4; ++r) {
        P1.row[r] = rows_[r]; P1.col[r] = cols_[r]; P1.w[r] = w[r]; P1.bk[r] = bk[r];
    }
    P1.choff = cnt1;
    P1.bktbase = bktbase;
    part1_k<<<dim3(NCH, 4), 256, 0, stream>>>(P1);

    Deg2P D2;
    D2.bk[0] = bk[0]; D2.bb[0] = bktbase + 0 * (NBKT + 1); D2.dinv[0] = dinv_gg;
    D2.bk[1] = bk[3]; D2.bb[1] = bktbase + 3 * (NBKT + 1); D2.dinv[1] = dinv_rr;
    deg2_k<<<dim3(NBKT, 2), 256, 0, stream>>>(D2);

    DegAP DA;
    DA.idx[0] = rows_[1]; DA.wgt[0] = w[1];
    DA.idx[1] = rows_[2]; DA.wgt[1] = w[2];
    DA.part = part_all;
    degAll_part_k<<<dim3(SB2 * 2, 2), 256, 0, stream>>>(DA);

    DegAS DAS;
    DAS.part = part_all;
    DAS.dinv[0] = dinv_gr_s;
    DAS.dinv[1] = dinv_rg_s;
    degAll_sum_k<<<dim3(ceil_div(NNODE, 256), 2), 256, 0, stream>>>(DAS);

    P2P P2;
    for (int r = 0; r < 4; ++r) { P2.bk[r] = bk[r]; P2.rowptr[r] = rowptr[r]; P2.ep[r] = ep[r]; }
    P2.bktbase = bktbase;
    P2.dS[0] = dinv_gg;   P2.dDg[0] = dinv_gg;   P2.self[0] = 1;
    P2.dS[1] = dinv_gr_s; P2.dDg[1] = nullptr;   P2.self[1] = 0;
    P2.dS[2] = dinv_rg_s; P2.dDg[2] = nullptr;   P2.self[2] = 0;
    P2.dS[3] = dinv_rr;   P2.dDg[3] = dinv_rr;   P2.self[3] = 1;
    part2_k<<<dim3(NBKT, 4), 256, 0, stream>>>(P2);

    CvtP CV;
    CV.in[0] = x_gen;  CV.out[0] = xh_gen;
    CV.in[1] = x_rain; CV.out[1] = xh_rain;
    cvt_k<<<dim3(NNODE * DF / 4 / 256, 2), 256, 0, stream>>>(CV);

    for (int l = 0; l < 2; ++l) {
        SpmmP SP;
        for (int r = 0; r < 4; ++r) { SP.rowptr[r] = rowptr[r]; SP.ep[r] = ep[r]; }
        SP.x[0] = xh_gen; SP.x[1] = xh_gen; SP.x[2] = xh_rain; SP.x[3] = xh_rain;
        SP.out[0] = aggh_gg; SP.out[1] = aggh_gr; SP.out[2] = aggh_rg; SP.out[3] = aggh_rr;
        spmm4_k<<<20000, 256, 0, stream>>>(SP);

        Gemm2P GP;
        GP.A1[0] = aggh_gg; GP.A2[0] = aggh_rg;
        GP.A1[1] = aggh_gr; GP.A2[1] = aggh_rr;
        GP.Wt[0] = WtH + (size_t)(l * 2 + 0) * 128 * 256;
        GP.Wt[1] = WtH + (size_t)(l * 2 + 1) * 128 * 256;
        GP.bs[0] = bsum + (l * 2 + 0) * 128;
        GP.bs[1] = bsum + (l * 2 + 1) * 128;
        GP.out[0] = xh_gen;
        GP.out[1] = xh_rain;
        gemm2_k<<<dim3(ceil_div(NNODE, 64), 2), 256, 0, stream>>>(GP);
    }

    Lin16P LP;
    LP.x[0] = xh_gen;  LP.W[0] = W_lg; LP.b[0] = b_lg; LP.out[0] = out_gen;
    LP.x[1] = xh_rain; LP.W[1] = W_lr; LP.b[1] = b_lr; LP.out[1] = out_rain;
    lin16_k<<<dim3(ceil_div(NNODE * DOUT, 256), 2), 256, 0, stream>>>(LP);
}

// Round 18
// 247.049 us; speedup vs baseline: 1.2110x; 1.0905x over previous
//
#include <hip/hip_runtime.h>
#include <hip/hip_fp16.h>

#define NNODE 20000
#define NE    600000
#define NES   (NE + NNODE)   // ep stride incl. self slots (used by gg, rr)
#define DF    128
#define DOUT  16
#define NBKT  80          // dst buckets
#define RNG   250         // nodes per bucket (80*250 = 20000 exact)
#define NCH   128         // partition chunks
#define CHE   4688        // edges per chunk (128*4688 >= NE)
#define P2CAP 12288       // part2 staging capacity
#define SB2   64          // degree chunks per stream
#define CS2   (NE/SB2)    // 9375

typedef _Float16 f16x8 __attribute__((ext_vector_type(8)));
typedef _Float16 f16x2 __attribute__((ext_vector_type(2)));
typedef float f32x4 __attribute__((ext_vector_type(4)));

static inline int ceil_div(int a, int b) { return (a + b - 1) / b; }

// ---------------- fp32 -> fp16 conversion ----------------
struct CvtP { const float* in[2]; __half* out[2]; };
__global__ __launch_bounds__(256) void cvt_k(CvtP P) {
    int g = blockIdx.y;
    int i = blockIdx.x * 256 + threadIdx.x;
    const float4* in = (const float4*)P.in[g];
    __half2* out = (__half2*)P.out[g];
    float4 v = in[i];
    out[2 * i + 0] = __floats2half2_rn(v.x, v.y);
    out[2 * i + 1] = __floats2half2_rn(v.z, v.w);
}

// ---------------- W prep: combined, transposed, fp16 + folded bias ----------------
__global__ __launch_bounds__(256) void prepW_k(const float* __restrict__ W_conv,
                                               const float* __restrict__ b_conv,
                                               __half* __restrict__ WtH,
                                               float* __restrict__ bsum) {
    int lg = blockIdx.y;
    int l = lg >> 1, g = lg & 1;
    int ra = (g == 0) ? 0 : 1;
    int rb = (g == 0) ? 2 : 3;
    int idx = blockIdx.x * 256 + threadIdx.x;
    int col = idx >> 8, k = idx & 255;
    const float* Wa = W_conv + (size_t)(l * 4 + ra) * 128 * 128;
    const float* Wb = W_conv + (size_t)(l * 4 + rb) * 128 * 128;
    float v = (k < 128) ? Wa[k * 128 + col] : Wb[(k - 128) * 128 + col];
    WtH[((size_t)lg * 128 + col) * 256 + k] = __float2half(v);
    if (idx < 128)
        bsum[lg * 128 + idx] = 0.5f * (b_conv[(l * 4 + ra) * 128 + idx] +
                                       b_conv[(l * 4 + rb) * 128 + idx]);
}

// ---------------- pass1: bucket counts (y 0..3) + src-degree partials (y 4..5) ----------------
struct Pass1P {
    const int* col[4]; int* cnt1;
    const int* idx[2]; const float* wgt[2]; float* part;
};
__global__ __launch_bounds__(256) void pass1_k(Pass1P P) {
    __shared__ float t[NNODE / 2];   // 40 KB (also hosts the small int histogram)
    int y = blockIdx.y;
    if (y < 4) {
        int* h = (int*)t;
        int ch = blockIdx.x, r = y;
        for (int i = threadIdx.x; i < NBKT; i += 256) h[i] = 0;
        __syncthreads();
        const int* col = P.col[r];
        int e0 = ch * CHE, e1 = min(NE, e0 + CHE);
        for (int e = e0 + threadIdx.x; e < e1; e += 256) atomicAdd(&h[col[e] / RNG], 1);
        __syncthreads();
        int* out = P.cnt1 + (size_t)r * NBKT * NCH;
        for (int b = threadIdx.x; b < NBKT; b += 256) out[b * NCH + ch] = h[b];
    } else {
        int s = y - 4;
        int chunk = blockIdx.x >> 1, half = blockIdx.x & 1;
        int nbase = half * (NNODE / 2);
        for (int i = threadIdx.x; i < NNODE / 2; i += 256) t[i] = 0.f;
        __syncthreads();
        const int* idx = P.idx[s];
        const float* w = P.wgt[s];
        int e0 = chunk * CS2, e1 = min(NE, e0 + CS2);
        for (int e = e0 + threadIdx.x; e < e1; e += 256) {
            int rr = idx[e] - nbase;
            if ((unsigned)rr < (unsigned)(NNODE / 2)) atomicAdd(&t[rr], w[e]);
        }
        __syncthreads();
        float* pp = P.part + ((size_t)s * SB2 + chunk) * NNODE + nbase;
        for (int i = threadIdx.x; i < NNODE / 2; i += 256) pp[i] = t[i];
    }
}

// ---------------- scans: chunk offsets within bucket + bucket bases ----------------
__global__ __launch_bounds__(128) void scan1_k(int* __restrict__ cnt1, int* __restrict__ bktbase) {
    __shared__ int tot[NBKT];
    int r = blockIdx.x;
    int* base = cnt1 + (size_t)r * NBKT * NCH;
    for (int b = threadIdx.x; b < NBKT; b += 128) {
        int run = 0;
        int* pb = base + b * NCH;
        for (int ch = 0; ch < NCH; ++ch) { int v = pb[ch]; pb[ch] = run; run += v; }
        tot[b] = run;
    }
    __syncthreads();
    if (threadIdx.x == 0) {
        int run = 0;
        int* bb = bktbase + r * (NBKT + 1);
        for (int b = 0; b < NBKT; ++b) { bb[b] = run; run += tot[b]; }
        bb[NBKT] = run;
    }
}

// ---------------- part1: sort chunk by bucket in LDS, flush runs coalesced ----------------
struct P1P {
    const int* row[4]; const int* col[4]; const float* w[4];
    const int* choff;
    const int* bktbase;
    uint2* bk[4];
};
__global__ __launch_bounds__(256) void part1_k(P1P P) {
    __shared__ uint2 st[CHE];
    __shared__ int h[NBKT];
    __shared__ int hoff[NBKT];
    __shared__ int c2[NBKT];
    int ch = blockIdx.x, r = blockIdx.y;
    for (int i = threadIdx.x; i < NBKT; i += 256) { h[i] = 0; c2[i] = 0; }
    __syncthreads();
    const int* col = P.col[r];
    const int* row = P.row[r];
    const float* w = P.w[r];
    int e0 = ch * CHE, e1 = min(NE, e0 + CHE);
    for (int e = e0 + threadIdx.x; e < e1; e += 256) atomicAdd(&h[col[e] / RNG], 1);
    __syncthreads();
    if (threadIdx.x == 0) {
        int run = 0;
        for (int b = 0; b < NBKT; ++b) { hoff[b] = run; run += h[b]; }
    }
    __syncthreads();
    for (int e = e0 + threadIdx.x; e < e1; e += 256) {
        int c = col[e];
        int b = c / RNG;
        int slot = hoff[b] + atomicAdd(&c2[b], 1);
        uint2 v;
        v.x = ((unsigned)c << 15) | (unsigned)row[e];
        v.y = (unsigned)__float_as_int(w[e]);
        st[slot] = v;
    }
    __syncthreads();
    const int* choff = P.choff + (size_t)r * NBKT * NCH;
    const int* bb = P.bktbase + r * (NBKT + 1);
    uint2* bk = P.bk[r];
    for (int b = 0; b < NBKT; ++b) {
        int base = bb[b] + choff[b * NCH + ch];
        int m = h[b];
        int lo = hoff[b];
        for (int i = threadIdx.x; i < m; i += 256) bk[base + i] = st[lo + i];
    }
}

// ---------------- pass2: gg/rr dst degrees from buckets (y 0..1) + src-degree reduce (y 2..3) ----------------
struct Pass2P {
    const uint2* bk[2]; const int* bb[2]; float* dinvD[2];
    const float* part; float* dinvS[2];
};
__global__ __launch_bounds__(256) void pass2_k(Pass2P P) {
    __shared__ float t[RNG];
    int y = blockIdx.y;
    if (y < 2) {
        int bkt = blockIdx.x, r2 = y;
        for (int i = threadIdx.x; i < RNG; i += 256) t[i] = 0.f;
        __syncthreads();
        const int* bb = P.bb[r2];
        int b0 = bb[bkt], n = bb[bkt + 1] - b0;
        const uint2* bk = P.bk[r2];
        int nlo = bkt * RNG;
        for (int i = threadIdx.x; i < n; i += 256) {
            uint2 rec = bk[b0 + i];
            atomicAdd(&t[(int)(rec.x >> 15) - nlo], __int_as_float((int)rec.y));
        }
        __syncthreads();
        float* dv = P.dinvD[r2];
        for (int c = threadIdx.x; c < RNG; c += 256) dv[nlo + c] = rsqrtf(t[c] + 1.0f);
    } else {
        int s = y - 2;
        int n = blockIdx.x * 256 + threadIdx.x;
        if (n >= NNODE) return;
        const float* pp = P.part + (size_t)s * SB2 * NNODE + n;
        float acc = 0.f;
        for (int c = 0; c < SB2; ++c) acc += pp[(size_t)c * NNODE];
        P.dinvS[s][n] = acc > 0.f ? rsqrtf(acc) : 0.f;
    }
}

// ---------------- part2: bucket -> CSR segment (parallel 256-slot scan) ----------------
struct P2P {
    const uint2* bk[4];
    const int* bktbase;
    const float* dS[4];
    const float* dDg[4];
    int self[4];
    int* rowptr[4];
    unsigned int* ep[4];
};
__global__ __launch_bounds__(256) void part2_k(P2P P) {
    __shared__ unsigned int st[P2CAP];
    __shared__ float wsum[RNG];
    __shared__ int cnt[RNG];
    __shared__ int off[RNG + 1];
    __shared__ int cur[RNG];
    __shared__ int sc[256];
    int bkt = blockIdx.x, r = blockIdx.y;
    int selfF = P.self[r];
    const int* bb = P.bktbase + r * (NBKT + 1);
    int b0 = bb[bkt], n = bb[bkt + 1] - b0;
    for (int i = threadIdx.x; i < RNG; i += 256) { wsum[i] = 0.f; cnt[i] = 0; cur[i] = 0; }
    __syncthreads();
    const uint2* bk = P.bk[r];
    int nlo = bkt * RNG;
    for (int i = threadIdx.x; i < n; i += 256) {
        uint2 rec = bk[b0 + i];
        int cl = (int)(rec.x >> 15) - nlo;
        atomicAdd(&cnt[cl], 1);
        if (!selfF) atomicAdd(&wsum[cl], __int_as_float((int)rec.y));
    }
    __syncthreads();
    int v = (threadIdx.x < RNG) ? cnt[threadIdx.x] + selfF : 0;
    sc[threadIdx.x] = v;
    __syncthreads();
    for (int o = 1; o < 256; o <<= 1) {
        int add = (threadIdx.x >= o) ? sc[threadIdx.x - o] : 0;
        __syncthreads();
        sc[threadIdx.x] += add;
        __syncthreads();
    }
    if (threadIdx.x < RNG) off[threadIdx.x] = sc[threadIdx.x] - v;
    if (threadIdx.x == 255) off[RNG] = sc[255];
    __syncthreads();
    int ntot = off[RNG];
    int epseg = b0 + (selfF ? nlo : 0);
    int* rp = P.rowptr[r];
    for (int c = threadIdx.x; c < RNG; c += 256) rp[nlo + c] = epseg + off[c];
    if (bkt == NBKT - 1 && threadIdx.x == 0) rp[NNODE] = epseg + ntot;
    const float* dDg = P.dDg[r];
    if (!selfF) {
        for (int c = threadIdx.x; c < RNG; c += 256) {
            float s = wsum[c];
            wsum[c] = s > 0.f ? rsqrtf(s) : 0.f;
        }
    }
    __syncthreads();
    if (selfF) {
        for (int c = threadIdx.x; c < RNG; c += 256) {
            float d = dDg[nlo + c];
            __half hh = __float2half(d * d);
            st[off[c]] = ((unsigned)(nlo + c) << 16) | *reinterpret_cast<unsigned short*>(&hh);
        }
    }
    const float* dS = P.dS[r];
    for (int i = threadIdx.x; i < n; i += 256) {
        uint2 rec = bk[b0 + i];
        int cg = (int)(rec.x >> 15);
        int cl = cg - nlo;
        int src = (int)(rec.x & 0x7fffu);
        float w = __int_as_float((int)rec.y);
        float dD = selfF ? dDg[cg] : wsum[cl];
        float nm = dS[src] * w * dD;
        int slot = off[cl] + selfF + atomicAdd(&cur[cl], 1);
        __half hh = __float2half(nm);
        st[slot] = ((unsigned)src << 16) | *reinterpret_cast<unsigned short*>(&hh);
    }
    __syncthreads();
    unsigned int* ep = P.ep[r];
    for (int i = threadIdx.x; i < ntot; i += 256) ep[epseg + i] = st[i];
}

// ---------------- pull-SpMM: quarter-wave gather, dot2 pairs (R12 proven form) ----------------
struct SpmmP {
    const __half* x[4]; const int* rowptr[4]; const unsigned int* ep[4]; __half* out[4];
};
__global__ __launch_bounds__(256) void spmm4_k(SpmmP P) {
    int b = blockIdx.x;
    int xcd = b & 7;
    int j = b >> 3;
    int r = ((xcd >> 2) << 1) + (j >= 1250 ? 1 : 0);
    int nodeblk = (xcd & 3) * 1250 + (j >= 1250 ? j - 1250 : j);
    int wid = nodeblk * 4 + (threadIdx.x >> 6);
    int lane = threadIdx.x & 63;
    int q = lane >> 4, c = lane & 15;
    const uint4* x4 = (const uint4*)P.x[r];
    const int* rp = P.rowptr[r];
    int bb = rp[wid], ee = rp[wid + 1];
    const unsigned int* ep = P.ep[r];
    float a[8];
#pragma unroll
    for (int t = 0; t < 8; ++t) a[t] = 0.f;

    auto decn = [](unsigned int v) -> float {
        unsigned short us = (unsigned short)(v & 0xffffu);
        __half h = *reinterpret_cast<__half*>(&us);
        return __half2float(h);
    };
    auto accum1 = [&](uint4 p, float n) {
        const __half2* ph = (const __half2*)&p;
#pragma unroll
        for (int t = 0; t < 4; ++t) {
            float2 f = __half22float2(ph[t]);
            a[2 * t]     = fmaf(f.x, n, a[2 * t]);
            a[2 * t + 1] = fmaf(f.y, n, a[2 * t + 1]);
        }
    };
    auto accum2 = [&](uint4 p0, uint4 p1, unsigned n01) {
        f16x2 nn = __builtin_bit_cast(f16x2, n01);
        const unsigned* u0 = (const unsigned*)&p0;
        const unsigned* u1 = (const unsigned*)&p1;
#pragma unroll
        for (int t = 0; t < 4; ++t) {
            unsigned plo = __builtin_amdgcn_perm(u1[t], u0[t], 0x05040100u);
            unsigned phi = __builtin_amdgcn_perm(u1[t], u0[t], 0x07060302u);
            a[2 * t]     = __builtin_amdgcn_fdot2(__builtin_bit_cast(f16x2, plo), nn, a[2 * t], false);
            a[2 * t + 1] = __builtin_amdgcn_fdot2(__builtin_bit_cast(f16x2, phi), nn, a[2 * t + 1], false);
        }
    };

    int i = bb + q;
    for (; i + 12 < ee; i += 16) {
        unsigned v0 = ep[i], v1 = ep[i + 4], v2 = ep[i + 8], v3 = ep[i + 12];
        uint4 p0 = x4[(size_t)(v0 >> 16) * 16 + c];
        uint4 p1 = x4[(size_t)(v1 >> 16) * 16 + c];
        uint4 p2 = x4[(size_t)(v2 >> 16) * 16 + c];
        uint4 p3 = x4[(size_t)(v3 >> 16) * 16 + c];
        accum2(p0, p1, __builtin_amdgcn_perm(v1, v0, 0x05040100u));
        accum2(p2, p3, __builtin_amdgcn_perm(v3, v2, 0x05040100u));
    }
    for (; i + 4 < ee; i += 8) {
        unsigned v0 = ep[i], v1 = ep[i + 4];
        uint4 p0 = x4[(size_t)(v0 >> 16) * 16 + c];
        uint4 p1 = x4[(size_t)(v1 >> 16) * 16 + c];
        accum2(p0, p1, __builtin_amdgcn_perm(v1, v0, 0x05040100u));
    }
    if (i < ee) {
        unsigned v0 = ep[i];
        uint4 p0 = x4[(size_t)(v0 >> 16) * 16 + c];
        accum1(p0, decn(v0));
    }
#pragma unroll
    for (int t = 0; t < 8; ++t) {
        a[t] += __shfl_xor(a[t], 16, 64);
        a[t] += __shfl_xor(a[t], 32, 64);
    }
    if (q == 0) {
        __half2 h[4];
#pragma unroll
        for (int t = 0; t < 4; ++t) h[t] = __floats2half2_rn(a[2 * t], a[2 * t + 1]);
        ((uint4*)P.out[r])[(size_t)wid * 16 + c] = *(uint4*)h;
    }
}

// ---------------- MFMA gemm2 (+ fused 128->16 head on the last layer) ----------------
struct Gemm2P {
    const __half* A1[2]; const __half* A2[2];
    const __half* Wt[2];
    const float* bs[2];
    __half* out[2];
    const float* Wh[2];   // head weights [128][16]
    const float* bh[2];   // head bias [16]
    float* out16[2];      // final fp32 outputs
    int last;
};
__global__ __launch_bounds__(256) void gemm2_k(Gemm2P P) {
    __shared__ __half sW[128 * 136];
    int g = blockIdx.y;
    int w = threadIdx.x >> 6, l = threadIdx.x & 63;
    int r0 = blockIdx.x * 64 + w * 16;
    int lm = l & 15, lh = l >> 4;
    f32x4 acc[8];
    f32x4 zero = {0.f, 0.f, 0.f, 0.f};
#pragma unroll
    for (int n = 0; n < 8; ++n) acc[n] = zero;
    const __half* As[2] = { P.A1[g], P.A2[g] };
    const uint4* wg = (const uint4*)P.Wt[g];
    int arow = r0 + lm;
    bool rok = arow < NNODE;
    for (int s = 0; s < 2; ++s) {
        __syncthreads();
        for (int u = threadIdx.x; u < 2048; u += 256) {
            int col = u >> 4, kb8 = u & 15;
            uint4 vv = wg[col * 32 + s * 16 + kb8];
            *(uint4*)&sW[col * 136 + kb8 * 8] = vv;
        }
        __syncthreads();
        const uint4* a4 = (const uint4*)As[s];
#pragma unroll
        for (int kk = 0; kk < 4; ++kk) {
            uint4 av = make_uint4(0, 0, 0, 0);
            if (rok) av = a4[(size_t)arow * 16 + kk * 4 + lh];
            f16x8 af = *(f16x8*)&av;
#pragma unroll
            for (int n = 0; n < 8; ++n) {
                uint4 bv = *(uint4*)&sW[(n * 16 + lm) * 136 + kk * 32 + lh * 8];
                f16x8 bf = *(f16x8*)&bv;
                acc[n] = __builtin_amdgcn_mfma_f32_16x16x32_f16(af, bf, acc[n], 0, 0, 0);
            }
        }
    }
    const float* bs = P.bs[g];
    if (!P.last) {
        __half* out = P.out[g];
#pragma unroll
        for (int n = 0; n < 8; ++n) {
            int colg = n * 16 + lm;
            float bb = bs[colg];
#pragma unroll
            for (int qq = 0; qq < 4; ++qq) {
                int rowg = r0 + lh * 4 + qq;
                if (rowg < NNODE) {
                    float v = fmaf(acc[n][qq], 0.5f, bb);
                    out[(size_t)rowg * 128 + colg] = __float2half(v > 0.f ? v : 0.f);
                }
            }
        }
    } else {
        // stage relu'd tile to LDS (per-wave 16x136 region), then fused 128->16 head
        __syncthreads();   // all waves done reading sW
        __half* tile = sW + (size_t)w * 16 * 136;
#pragma unroll
        for (int n = 0; n < 8; ++n) {
            int colg = n * 16 + lm;
            float bb = bs[colg];
#pragma unroll
            for (int qq = 0; qq < 4; ++qq) {
                int rowl = lh * 4 + qq;
                float v = fmaf(acc[n][qq], 0.5f, bb);
                tile[rowl * 136 + colg] = __float2half(v > 0.f ? v : 0.f);
            }
        }
        // intra-wave LDS dependency only; compiler inserts lgkmcnt waits
        const float* Wh = P.Wh[g];
        const float* bh = P.bh[g];
        int row = l & 15, grp = l >> 4;   // 4 cols per lane group
        int rowg = r0 + row;
        float a4[4];
#pragma unroll
        for (int c = 0; c < 4; ++c) a4[c] = bh[grp * 4 + c];
        for (int k = 0; k < 128; ++k) {
            float tv = __half2float(tile[row * 136 + k]);
#pragma unroll
            for (int c = 0; c < 4; ++c) a4[c] = fmaf(tv, Wh[k * 16 + grp * 4 + c], a4[c]);
        }
        if (rowg < NNODE) {
            float4 vv = make_float4(a4[0], a4[1], a4[2], a4[3]);
            *(float4*)&P.out16[g][(size_t)rowg * 16 + grp * 4] = vv;
        }
    }
}

extern "C" void kernel_launch(void* const* d_in, const int* in_sizes, int n_in,
                              void* d_out, int out_size, void* d_ws, size_t ws_size,
                              hipStream_t stream) {
    (void)in_sizes; (void)n_in; (void)out_size; (void)ws_size;

    const float* x_gen  = (const float*)d_in[0];
    const float* x_rain = (const float*)d_in[1];
    const int* ei[4] = {(const int*)d_in[2], (const int*)d_in[3], (const int*)d_in[4], (const int*)d_in[5]};
    const float* w[4] = {(const float*)d_in[6], (const float*)d_in[7], (const float*)d_in[8], (const float*)d_in[9]};
    const float* W_conv = (const float*)d_in[10];
    const float* b_conv = (const float*)d_in[11];
    const float* W_lg = (const float*)d_in[12];
    const float* b_lg = (const float*)d_in[13];
    const float* W_lr = (const float*)d_in[14];
    const float* b_lr = (const float*)d_in[15];

    float* out_gen  = (float*)d_out;
    float* out_rain = out_gen + (size_t)NNODE * DOUT;

    char* p = (char*)d_ws;
    auto alloc = [&](size_t bytes) -> void* {
        void* r = (void*)p;
        p += (bytes + 255) & ~(size_t)255;
        return r;
    };

    float* deg = (float*)alloc(4 * (size_t)NNODE * sizeof(float));
    float* dinv_gg   = deg + 0 * NNODE;
    float* dinv_rr   = deg + 1 * NNODE;
    float* dinv_gr_s = deg + 2 * NNODE;
    float* dinv_rg_s = deg + 3 * NNODE;

    int* rowptr_all = (int*)alloc(4 * (size_t)(NNODE + 1) * sizeof(int));
    int* cnt1       = (int*)alloc(4 * (size_t)NBKT * NCH * sizeof(int));
    int* bktbase    = (int*)alloc(4 * (size_t)(NBKT + 1) * sizeof(int));

    size_t epack_bytes = 4 * (size_t)NES * sizeof(unsigned int);
    size_t part_bytes  = 2 * (size_t)SB2 * NNODE * sizeof(float);
    unsigned int* epack_all = (unsigned int*)alloc(epack_bytes > part_bytes ? epack_bytes : part_bytes);
    float* part_all = (float*)epack_all;

    __half* agg_all = (__half*)alloc(4 * (size_t)NNODE * DF * sizeof(__half));
    __half* aggh_gg = agg_all + 0 * (size_t)NNODE * DF;
    __half* aggh_gr = agg_all + 1 * (size_t)NNODE * DF;
    __half* aggh_rg = agg_all + 2 * (size_t)NNODE * DF;
    __half* aggh_rr = agg_all + 3 * (size_t)NNODE * DF;
    uint2* bk_all = (uint2*)agg_all;

    __half* xh_gen  = (__half*)alloc((size_t)NNODE * DF * sizeof(__half));
    __half* xh_rain = (__half*)alloc((size_t)NNODE * DF * sizeof(__half));
    __half* WtH  = (__half*)alloc(4 * (size_t)128 * 256 * sizeof(__half));
    float*  bsum = (float*)alloc(4 * 128 * sizeof(float));

    int* rowptr[4]; unsigned int* ep[4]; uint2* bk[4];
    for (int r = 0; r < 4; ++r) {
        rowptr[r] = rowptr_all + (size_t)r * (NNODE + 1);
        ep[r]     = epack_all + (size_t)r * NES;
        bk[r]     = bk_all + (size_t)r * NE;
    }

    const int* rows_[4] = {ei[0], ei[1], ei[2], ei[3]};
    const int* cols_[4] = {ei[0] + NE, ei[1] + NE, ei[2] + NE, ei[3] + NE};

    prepW_k<<<dim3(128, 4), 256, 0, stream>>>(W_conv, b_conv, WtH, bsum);

    // pass1: bucket counts (4 relations) + src-degree partials (gr, rg)
    Pass1P PA;
    for (int r = 0; r < 4; ++r) PA.col[r] = cols_[r];
    PA.cnt1 = cnt1;
    PA.idx[0] = rows_[1]; PA.wgt[0] = w[1];
    PA.idx[1] = rows_[2]; PA.wgt[1] = w[2];
    PA.part = part_all;
    pass1_k<<<dim3(NCH, 6), 256, 0, stream>>>(PA);

    scan1_k<<<4, 128, 0, stream>>>(cnt1, bktbase);

    P1P P1;
    for (int r = 0; r < 4; ++r) {
        P1.row[r] = rows_[r]; P1.col[r] = cols_[r]; P1.w[r] = w[r]; P1.bk[r] = bk[r];
    }
    P1.choff = cnt1;
    P1.bktbase = bktbase;
    part1_k<<<dim3(NCH, 4), 256, 0, stream>>>(P1);

    // pass2: gg/rr dst degrees from buckets + src-degree reduce
    Pass2P PB;
    PB.bk[0] = bk[0]; PB.bb[0] = bktbase + 0 * (NBKT + 1); PB.dinvD[0] = dinv_gg;
    PB.bk[1] = bk[3]; PB.bb[1] = bktbase + 3 * (NBKT + 1); PB.dinvD[1] = dinv_rr;
    PB.part = part_all;
    PB.dinvS[0] = dinv_gr_s;
    PB.dinvS[1] = dinv_rg_s;
    pass2_k<<<dim3(NBKT, 4), 256, 0, stream>>>(PB);

    P2P P2;
    for (int r = 0; r < 4; ++r) { P2.bk[r] = bk[r]; P2.rowptr[r] = rowptr[r]; P2.ep[r] = ep[r]; }
    P2.bktbase = bktbase;
    P2.dS[0] = dinv_gg;   P2.dDg[0] = dinv_gg;   P2.self[0] = 1;
    P2.dS[1] = dinv_gr_s; P2.dDg[1] = nullptr;   P2.self[1] = 0;
    P2.dS[2] = dinv_rg_s; P2.dDg[2] = nullptr;   P2.self[2] = 0;
    P2.dS[3] = dinv_rr;   P2.dDg[3] = dinv_rr;   P2.self[3] = 1;
    part2_k<<<dim3(NBKT, 4), 256, 0, stream>>>(P2);

    CvtP CV;
    CV.in[0] = x_gen;  CV.out[0] = xh_gen;
    CV.in[1] = x_rain; CV.out[1] = xh_rain;
    cvt_k<<<dim3(NNODE * DF / 4 / 256, 2), 256, 0, stream>>>(CV);

    for (int l = 0; l < 2; ++l) {
        SpmmP SP;
        for (int r = 0; r < 4; ++r) { SP.rowptr[r] = rowptr[r]; SP.ep[r] = ep[r]; }
        SP.x[0] = xh_gen; SP.x[1] = xh_gen; SP.x[2] = xh_rain; SP.x[3] = xh_rain;
        SP.out[0] = aggh_gg; SP.out[1] = aggh_gr; SP.out[2] = aggh_rg; SP.out[3] = aggh_rr;
        spmm4_k<<<20000, 256, 0, stream>>>(SP);

        Gemm2P GP;
        GP.A1[0] = aggh_gg; GP.A2[0] = aggh_rg;
        GP.A1[1] = aggh_gr; GP.A2[1] = aggh_rr;
        GP.Wt[0] = WtH + (size_t)(l * 2 + 0) * 128 * 256;
        GP.Wt[1] = WtH + (size_t)(l * 2 + 1) * 128 * 256;
        GP.bs[0] = bsum + (l * 2 + 0) * 128;
        GP.bs[1] = bsum + (l * 2 + 1) * 128;
        GP.out[0] = xh_gen;
        GP.out[1] = xh_rain;
        GP.Wh[0] = W_lg; GP.bh[0] = b_lg; GP.out16[0] = out_gen;
        GP.Wh[1] = W_lr; GP.bh[1] = b_lr; GP.out16[1] = out_rain;
        GP.last = (l == 1);
        gemm2_k<<<dim3(ceil_div(NNODE, 64), 2), 256, 0, stream>>>(GP);
    }
}

// Round 19
// 244.196 us; speedup vs baseline: 1.2252x; 1.0117x over previous
//
#include <hip/hip_runtime.h>
#include <hip/hip_fp16.h>

#define NNODE 20000
#define NE    600000
#define NES   (NE + NNODE)   // ep stride incl. self slots (used by gg, rr)
#define DF    128
#define DOUT  16
#define NBKT  80          // dst buckets
#define RNG   250         // nodes per bucket (80*250 = 20000 exact)
#define NCH   128         // partition chunks
#define CHE   4688        // edges per chunk (128*4688 >= NE)
#define P2CAP 12288       // part2 staging capacity
#define SB2   64          // degree chunks per stream
#define CS2   (NE/SB2)    // 9375

typedef _Float16 f16x8 __attribute__((ext_vector_type(8)));
typedef _Float16 f16x2 __attribute__((ext_vector_type(2)));
typedef float f32x4 __attribute__((ext_vector_type(4)));

static inline int ceil_div(int a, int b) { return (a + b - 1) / b; }

// ---------------- fp32 -> fp16 conversion ----------------
struct CvtP { const float* in[2]; __half* out[2]; };
__global__ __launch_bounds__(256) void cvt_k(CvtP P) {
    int g = blockIdx.y;
    int i = blockIdx.x * 256 + threadIdx.x;
    const float4* in = (const float4*)P.in[g];
    __half2* out = (__half2*)P.out[g];
    float4 v = in[i];
    out[2 * i + 0] = __floats2half2_rn(v.x, v.y);
    out[2 * i + 1] = __floats2half2_rn(v.z, v.w);
}

// ---------------- W prep: combined, transposed, fp16 + folded bias ----------------
__global__ __launch_bounds__(256) void prepW_k(const float* __restrict__ W_conv,
                                               const float* __restrict__ b_conv,
                                               __half* __restrict__ WtH,
                                               float* __restrict__ bsum) {
    int lg = blockIdx.y;
    int l = lg >> 1, g = lg & 1;
    int ra = (g == 0) ? 0 : 1;
    int rb = (g == 0) ? 2 : 3;
    int idx = blockIdx.x * 256 + threadIdx.x;
    int col = idx >> 8, k = idx & 255;
    const float* Wa = W_conv + (size_t)(l * 4 + ra) * 128 * 128;
    const float* Wb = W_conv + (size_t)(l * 4 + rb) * 128 * 128;
    float v = (k < 128) ? Wa[k * 128 + col] : Wb[(k - 128) * 128 + col];
    WtH[((size_t)lg * 128 + col) * 256 + k] = __float2half(v);
    if (idx < 128)
        bsum[lg * 128 + idx] = 0.5f * (b_conv[(l * 4 + ra) * 128 + idx] +
                                       b_conv[(l * 4 + rb) * 128 + idx]);
}

// ---------------- pass1: bucket counts (y 0..3) + src-degree partials (y 4..5) ----------------
struct Pass1P {
    const int* col[4]; int* cnt1;
    const int* idx[2]; const float* wgt[2]; float* part;
};
__global__ __launch_bounds__(256) void pass1_k(Pass1P P) {
    __shared__ float t[NNODE / 2];   // 40 KB (also hosts the small int histogram)
    int y = blockIdx.y;
    if (y < 4) {
        int* h = (int*)t;
        int ch = blockIdx.x, r = y;
        for (int i = threadIdx.x; i < NBKT; i += 256) h[i] = 0;
        __syncthreads();
        const int* col = P.col[r];
        int e0 = ch * CHE, e1 = min(NE, e0 + CHE);
        for (int e = e0 + threadIdx.x; e < e1; e += 256) atomicAdd(&h[col[e] / RNG], 1);
        __syncthreads();
        int* out = P.cnt1 + (size_t)r * NBKT * NCH;
        for (int b = threadIdx.x; b < NBKT; b += 256) out[b * NCH + ch] = h[b];
    } else {
        int s = y - 4;
        int chunk = blockIdx.x >> 1, half = blockIdx.x & 1;
        int nbase = half * (NNODE / 2);
        for (int i = threadIdx.x; i < NNODE / 2; i += 256) t[i] = 0.f;
        __syncthreads();
        const int* idx = P.idx[s];
        const float* w = P.wgt[s];
        int e0 = chunk * CS2, e1 = min(NE, e0 + CS2);
        for (int e = e0 + threadIdx.x; e < e1; e += 256) {
            int rr = idx[e] - nbase;
            if ((unsigned)rr < (unsigned)(NNODE / 2)) atomicAdd(&t[rr], w[e]);
        }
        __syncthreads();
        float* pp = P.part + ((size_t)s * SB2 + chunk) * NNODE + nbase;
        for (int i = threadIdx.x; i < NNODE / 2; i += 256) pp[i] = t[i];
    }
}

// ---------------- scans: chunk offsets within bucket + bucket bases ----------------
__global__ __launch_bounds__(128) void scan1_k(int* __restrict__ cnt1, int* __restrict__ bktbase) {
    __shared__ int tot[NBKT];
    int r = blockIdx.x;
    int* base = cnt1 + (size_t)r * NBKT * NCH;
    for (int b = threadIdx.x; b < NBKT; b += 128) {
        int run = 0;
        int* pb = base + b * NCH;
        for (int ch = 0; ch < NCH; ++ch) { int v = pb[ch]; pb[ch] = run; run += v; }
        tot[b] = run;
    }
    __syncthreads();
    if (threadIdx.x == 0) {
        int run = 0;
        int* bb = bktbase + r * (NBKT + 1);
        for (int b = 0; b < NBKT; ++b) { bb[b] = run; run += tot[b]; }
        bb[NBKT] = run;
    }
}

// ---------------- part1: counts derived from scanned cnt1, single edge pass ----------------
struct P1P {
    const int* row[4]; const int* col[4]; const float* w[4];
    const int* choff;   // scanned cnt1: [r][bkt][ch] exclusive offsets within bucket
    const int* bktbase;
    uint2* bk[4];
};
__global__ __launch_bounds__(256) void part1_k(P1P P) {
    __shared__ uint2 st[CHE];
    __shared__ int h[NBKT];
    __shared__ int hoff[NBKT];
    __shared__ int c2[NBKT];
    __shared__ int sc[128];
    int ch = blockIdx.x, r = blockIdx.y;
    const int* choff = P.choff + (size_t)r * NBKT * NCH;
    const int* bb = P.bktbase + r * (NBKT + 1);
    // derive per-bucket counts for this chunk from the scanned offsets
    for (int b = threadIdx.x; b < NBKT; b += 256) {
        int lo = choff[b * NCH + ch];
        int hi = (ch < NCH - 1) ? choff[b * NCH + ch + 1] : (bb[b + 1] - bb[b]);
        h[b] = hi - lo;
        c2[b] = 0;
    }
    __syncthreads();
    // exclusive prefix over h (128-slot Hillis-Steele covers NBKT=80)
    int v = 0;
    if (threadIdx.x < 128) {
        v = (threadIdx.x < NBKT) ? h[threadIdx.x] : 0;
        sc[threadIdx.x] = v;
    }
    __syncthreads();
    for (int o = 1; o < 128; o <<= 1) {
        int add = 0;
        if (threadIdx.x < 128 && threadIdx.x >= o) add = sc[threadIdx.x - o];
        __syncthreads();
        if (threadIdx.x < 128) sc[threadIdx.x] += add;
        __syncthreads();
    }
    if (threadIdx.x < NBKT) hoff[threadIdx.x] = sc[threadIdx.x] - v;
    __syncthreads();
    const int* col = P.col[r];
    const int* row = P.row[r];
    const float* w = P.w[r];
    int e0 = ch * CHE, e1 = min(NE, e0 + CHE);
    for (int e = e0 + threadIdx.x; e < e1; e += 256) {
        int c = col[e];
        int b = c / RNG;
        int slot = hoff[b] + atomicAdd(&c2[b], 1);
        uint2 rec;
        rec.x = ((unsigned)c << 15) | (unsigned)row[e];
        rec.y = (unsigned)__float_as_int(w[e]);
        st[slot] = rec;
    }
    __syncthreads();
    uint2* bk = P.bk[r];
    for (int b = 0; b < NBKT; ++b) {
        int base = bb[b] + choff[b * NCH + ch];
        int m = h[b];
        int lo = hoff[b];
        for (int i = threadIdx.x; i < m; i += 256) bk[base + i] = st[lo + i];
    }
}

// ---------------- pass2: gg/rr dst degrees from buckets (y 0..1) + src-degree reduce (y 2..3) ----------------
struct Pass2P {
    const uint2* bk[2]; const int* bb[2]; float* dinvD[2];
    const float* part; float* dinvS[2];
};
__global__ __launch_bounds__(256) void pass2_k(Pass2P P) {
    __shared__ float t[RNG];
    int y = blockIdx.y;
    if (y < 2) {
        int bkt = blockIdx.x, r2 = y;
        for (int i = threadIdx.x; i < RNG; i += 256) t[i] = 0.f;
        __syncthreads();
        const int* bb = P.bb[r2];
        int b0 = bb[bkt], n = bb[bkt + 1] - b0;
        const uint2* bk = P.bk[r2];
        int nlo = bkt * RNG;
        for (int i = threadIdx.x; i < n; i += 256) {
            uint2 rec = bk[b0 + i];
            atomicAdd(&t[(int)(rec.x >> 15) - nlo], __int_as_float((int)rec.y));
        }
        __syncthreads();
        float* dv = P.dinvD[r2];
        for (int c = threadIdx.x; c < RNG; c += 256) dv[nlo + c] = rsqrtf(t[c] + 1.0f);
    } else {
        int s = y - 2;
        int n = blockIdx.x * 256 + threadIdx.x;
        if (n >= NNODE) return;
        const float* pp = P.part + (size_t)s * SB2 * NNODE + n;
        float acc = 0.f;
        for (int c = 0; c < SB2; ++c) acc += pp[(size_t)c * NNODE];
        P.dinvS[s][n] = acc > 0.f ? rsqrtf(acc) : 0.f;
    }
}

// ---------------- part2: bucket -> CSR segment (parallel 256-slot scan) ----------------
struct P2P {
    const uint2* bk[4];
    const int* bktbase;
    const float* dS[4];
    const float* dDg[4];
    int self[4];
    int* rowptr[4];
    unsigned int* ep[4];
};
__global__ __launch_bounds__(256) void part2_k(P2P P) {
    __shared__ unsigned int st[P2CAP];
    __shared__ float wsum[RNG];
    __shared__ int cnt[RNG];
    __shared__ int off[RNG + 1];
    __shared__ int cur[RNG];
    __shared__ int sc[256];
    int bkt = blockIdx.x, r = blockIdx.y;
    int selfF = P.self[r];
    const int* bb = P.bktbase + r * (NBKT + 1);
    int b0 = bb[bkt], n = bb[bkt + 1] - b0;
    for (int i = threadIdx.x; i < RNG; i += 256) { wsum[i] = 0.f; cnt[i] = 0; cur[i] = 0; }
    __syncthreads();
    const uint2* bk = P.bk[r];
    int nlo = bkt * RNG;
    for (int i = threadIdx.x; i < n; i += 256) {
        uint2 rec = bk[b0 + i];
        int cl = (int)(rec.x >> 15) - nlo;
        atomicAdd(&cnt[cl], 1);
        if (!selfF) atomicAdd(&wsum[cl], __int_as_float((int)rec.y));
    }
    __syncthreads();
    int v = (threadIdx.x < RNG) ? cnt[threadIdx.x] + selfF : 0;
    sc[threadIdx.x] = v;
    __syncthreads();
    for (int o = 1; o < 256; o <<= 1) {
        int add = (threadIdx.x >= o) ? sc[threadIdx.x - o] : 0;
        __syncthreads();
        sc[threadIdx.x] += add;
        __syncthreads();
    }
    if (threadIdx.x < RNG) off[threadIdx.x] = sc[threadIdx.x] - v;
    if (threadIdx.x == 255) off[RNG] = sc[255];
    __syncthreads();
    int ntot = off[RNG];
    int epseg = b0 + (selfF ? nlo : 0);
    int* rp = P.rowptr[r];
    for (int c = threadIdx.x; c < RNG; c += 256) rp[nlo + c] = epseg + off[c];
    if (bkt == NBKT - 1 && threadIdx.x == 0) rp[NNODE] = epseg + ntot;
    const float* dDg = P.dDg[r];
    if (!selfF) {
        for (int c = threadIdx.x; c < RNG; c += 256) {
            float s = wsum[c];
            wsum[c] = s > 0.f ? rsqrtf(s) : 0.f;
        }
    }
    __syncthreads();
    if (selfF) {
        for (int c = threadIdx.x; c < RNG; c += 256) {
            float d = dDg[nlo + c];
            __half hh = __float2half(d * d);
            st[off[c]] = ((unsigned)(nlo + c) << 16) | *reinterpret_cast<unsigned short*>(&hh);
        }
    }
    const float* dS = P.dS[r];
    for (int i = threadIdx.x; i < n; i += 256) {
        uint2 rec = bk[b0 + i];
        int cg = (int)(rec.x >> 15);
        int cl = cg - nlo;
        int src = (int)(rec.x & 0x7fffu);
        float w = __int_as_float((int)rec.y);
        float dD = selfF ? dDg[cg] : wsum[cl];
        float nm = dS[src] * w * dD;
        int slot = off[cl] + selfF + atomicAdd(&cur[cl], 1);
        __half hh = __float2half(nm);
        st[slot] = ((unsigned)src << 16) | *reinterpret_cast<unsigned short*>(&hh);
    }
    __syncthreads();
    unsigned int* ep = P.ep[r];
    for (int i = threadIdx.x; i < ntot; i += 256) ep[epseg + i] = st[i];
}

// ---------------- pull-SpMM: quarter-wave gather, dot2 pairs (R12 proven form) ----------------
struct SpmmP {
    const __half* x[4]; const int* rowptr[4]; const unsigned int* ep[4]; __half* out[4];
};
__global__ __launch_bounds__(256) void spmm4_k(SpmmP P) {
    int b = blockIdx.x;
    int xcd = b & 7;
    int j = b >> 3;
    int r = ((xcd >> 2) << 1) + (j >= 1250 ? 1 : 0);
    int nodeblk = (xcd & 3) * 1250 + (j >= 1250 ? j - 1250 : j);
    int wid = nodeblk * 4 + (threadIdx.x >> 6);
    int lane = threadIdx.x & 63;
    int q = lane >> 4, c = lane & 15;
    const uint4* x4 = (const uint4*)P.x[r];
    const int* rp = P.rowptr[r];
    int bb = rp[wid], ee = rp[wid + 1];
    const unsigned int* ep = P.ep[r];
    float a[8];
#pragma unroll
    for (int t = 0; t < 8; ++t) a[t] = 0.f;

    auto decn = [](unsigned int v) -> float {
        unsigned short us = (unsigned short)(v & 0xffffu);
        __half h = *reinterpret_cast<__half*>(&us);
        return __half2float(h);
    };
    auto accum1 = [&](uint4 p, float n) {
        const __half2* ph = (const __half2*)&p;
#pragma unroll
        for (int t = 0; t < 4; ++t) {
            float2 f = __half22float2(ph[t]);
            a[2 * t]     = fmaf(f.x, n, a[2 * t]);
            a[2 * t + 1] = fmaf(f.y, n, a[2 * t + 1]);
        }
    };
    auto accum2 = [&](uint4 p0, uint4 p1, unsigned n01) {
        f16x2 nn = __builtin_bit_cast(f16x2, n01);
        const unsigned* u0 = (const unsigned*)&p0;
        const unsigned* u1 = (const unsigned*)&p1;
#pragma unroll
        for (int t = 0; t < 4; ++t) {
            unsigned plo = __builtin_amdgcn_perm(u1[t], u0[t], 0x05040100u);
            unsigned phi = __builtin_amdgcn_perm(u1[t], u0[t], 0x07060302u);
            a[2 * t]     = __builtin_amdgcn_fdot2(__builtin_bit_cast(f16x2, plo), nn, a[2 * t], false);
            a[2 * t + 1] = __builtin_amdgcn_fdot2(__builtin_bit_cast(f16x2, phi), nn, a[2 * t + 1], false);
        }
    };

    int i = bb + q;
    for (; i + 12 < ee; i += 16) {
        unsigned v0 = ep[i], v1 = ep[i + 4], v2 = ep[i + 8], v3 = ep[i + 12];
        uint4 p0 = x4[(size_t)(v0 >> 16) * 16 + c];
        uint4 p1 = x4[(size_t)(v1 >> 16) * 16 + c];
        uint4 p2 = x4[(size_t)(v2 >> 16) * 16 + c];
        uint4 p3 = x4[(size_t)(v3 >> 16) * 16 + c];
        accum2(p0, p1, __builtin_amdgcn_perm(v1, v0, 0x05040100u));
        accum2(p2, p3, __builtin_amdgcn_perm(v3, v2, 0x05040100u));
    }
    for (; i + 4 < ee; i += 8) {
        unsigned v0 = ep[i], v1 = ep[i + 4];
        uint4 p0 = x4[(size_t)(v0 >> 16) * 16 + c];
        uint4 p1 = x4[(size_t)(v1 >> 16) * 16 + c];
        accum2(p0, p1, __builtin_amdgcn_perm(v1, v0, 0x05040100u));
    }
    if (i < ee) {
        unsigned v0 = ep[i];
        uint4 p0 = x4[(size_t)(v0 >> 16) * 16 + c];
        accum1(p0, decn(v0));
    }
#pragma unroll
    for (int t = 0; t < 8; ++t) {
        a[t] += __shfl_xor(a[t], 16, 64);
        a[t] += __shfl_xor(a[t], 32, 64);
    }
    if (q == 0) {
        __half2 h[4];
#pragma unroll
        for (int t = 0; t < 4; ++t) h[t] = __floats2half2_rn(a[2 * t], a[2 * t + 1]);
        ((uint4*)P.out[r])[(size_t)wid * 16 + c] = *(uint4*)h;
    }
}

// ---------------- MFMA gemm2 (+ fused 128->16 head on the last layer) ----------------
struct Gemm2P {
    const __half* A1[2]; const __half* A2[2];
    const __half* Wt[2];
    const float* bs[2];
    __half* out[2];
    const float* Wh[2];   // head weights [128][16]
    const float* bh[2];   // head bias [16]
    float* out16[2];      // final fp32 outputs
    int last;
};
__global__ __launch_bounds__(256) void gemm2_k(Gemm2P P) {
    __shared__ __half sW[128 * 136];
    int g = blockIdx.y;
    int w = threadIdx.x >> 6, l = threadIdx.x & 63;
    int r0 = blockIdx.x * 64 + w * 16;
    int lm = l & 15, lh = l >> 4;
    f32x4 acc[8];
    f32x4 zero = {0.f, 0.f, 0.f, 0.f};
#pragma unroll
    for (int n = 0; n < 8; ++n) acc[n] = zero;
    const __half* As[2] = { P.A1[g], P.A2[g] };
    const uint4* wg = (const uint4*)P.Wt[g];
    int arow = r0 + lm;
    bool rok = arow < NNODE;
    for (int s = 0; s < 2; ++s) {
        __syncthreads();
        for (int u = threadIdx.x; u < 2048; u += 256) {
            int col = u >> 4, kb8 = u & 15;
            uint4 vv = wg[col * 32 + s * 16 + kb8];
            *(uint4*)&sW[col * 136 + kb8 * 8] = vv;
        }
        __syncthreads();
        const uint4* a4 = (const uint4*)As[s];
#pragma unroll
        for (int kk = 0; kk < 4; ++kk) {
            uint4 av = make_uint4(0, 0, 0, 0);
            if (rok) av = a4[(size_t)arow * 16 + kk * 4 + lh];
            f16x8 af = *(f16x8*)&av;
#pragma unroll
            for (int n = 0; n < 8; ++n) {
                uint4 bv = *(uint4*)&sW[(n * 16 + lm) * 136 + kk * 32 + lh * 8];
                f16x8 bf = *(f16x8*)&bv;
                acc[n] = __builtin_amdgcn_mfma_f32_16x16x32_f16(af, bf, acc[n], 0, 0, 0);
            }
        }
    }
    const float* bs = P.bs[g];
    if (!P.last) {
        __half* out = P.out[g];
#pragma unroll
        for (int n = 0; n < 8; ++n) {
            int colg = n * 16 + lm;
            float bb = bs[colg];
#pragma unroll
            for (int qq = 0; qq < 4; ++qq) {
                int rowg = r0 + lh * 4 + qq;
                if (rowg < NNODE) {
                    float v = fmaf(acc[n][qq], 0.5f, bb);
                    out[(size_t)rowg * 128 + colg] = __float2half(v > 0.f ? v : 0.f);
                }
            }
        }
    } else {
        __syncthreads();   // all waves done reading sW
        __half* tile = sW + (size_t)w * 16 * 136;
#pragma unroll
        for (int n = 0; n < 8; ++n) {
            int colg = n * 16 + lm;
            float bb = bs[colg];
#pragma unroll
            for (int qq = 0; qq < 4; ++qq) {
                int rowl = lh * 4 + qq;
                float v = fmaf(acc[n][qq], 0.5f, bb);
                tile[rowl * 136 + colg] = __float2half(v > 0.f ? v : 0.f);
            }
        }
        const float* Wh = P.Wh[g];
        const float* bh = P.bh[g];
        int row = l & 15, grp = l >> 4;   // 4 cols per lane group
        int rowg = r0 + row;
        float a4[4];
#pragma unroll
        for (int c = 0; c < 4; ++c) a4[c] = bh[grp * 4 + c];
        for (int k = 0; k < 128; ++k) {
            float tv = __half2float(tile[row * 136 + k]);
#pragma unroll
            for (int c = 0; c < 4; ++c) a4[c] = fmaf(tv, Wh[k * 16 + grp * 4 + c], a4[c]);
        }
        if (rowg < NNODE) {
            float4 vv = make_float4(a4[0], a4[1], a4[2], a4[3]);
            *(float4*)&P.out16[g][(size_t)rowg * 16 + grp * 4] = vv;
        }
    }
}

extern "C" void kernel_launch(void* const* d_in, const int* in_sizes, int n_in,
                              void* d_out, int out_size, void* d_ws, size_t ws_size,
                              hipStream_t stream) {
    (void)in_sizes; (void)n_in; (void)out_size; (void)ws_size;

    const float* x_gen  = (const float*)d_in[0];
    const float* x_rain = (const float*)d_in[1];
    const int* ei[4] = {(const int*)d_in[2], (const int*)d_in[3], (const int*)d_in[4], (const int*)d_in[5]};
    const float* w[4] = {(const float*)d_in[6], (const float*)d_in[7], (const float*)d_in[8], (const float*)d_in[9]};
    const float* W_conv = (const float*)d_in[10];
    const float* b_conv = (const float*)d_in[11];
    const float* W_lg = (const float*)d_in[12];
    const float* b_lg = (const float*)d_in[13];
    const float* W_lr = (const float*)d_in[14];
    const float* b_lr = (const float*)d_in[15];

    float* out_gen  = (float*)d_out;
    float* out_rain = out_gen + (size_t)NNODE * DOUT;

    char* p = (char*)d_ws;
    auto alloc = [&](size_t bytes) -> void* {
        void* r = (void*)p;
        p += (bytes + 255) & ~(size_t)255;
        return r;
    };

    float* deg = (float*)alloc(4 * (size_t)NNODE * sizeof(float));
    float* dinv_gg   = deg + 0 * NNODE;
    float* dinv_rr   = deg + 1 * NNODE;
    float* dinv_gr_s = deg + 2 * NNODE;
    float* dinv_rg_s = deg + 3 * NNODE;

    int* rowptr_all = (int*)alloc(4 * (size_t)(NNODE + 1) * sizeof(int));
    int* cnt1       = (int*)alloc(4 * (size_t)NBKT * NCH * sizeof(int));
    int* bktbase    = (int*)alloc(4 * (size_t)(NBKT + 1) * sizeof(int));

    size_t epack_bytes = 4 * (size_t)NES * sizeof(unsigned int);
    size_t part_bytes  = 2 * (size_t)SB2 * NNODE * sizeof(float);
    unsigned int* epack_all = (unsigned int*)alloc(epack_bytes > part_bytes ? epack_bytes : part_bytes);
    float* part_all = (float*)epack_all;

    __half* agg_all = (__half*)alloc(4 * (size_t)NNODE * DF * sizeof(__half));
    __half* aggh_gg = agg_all + 0 * (size_t)NNODE * DF;
    __half* aggh_gr = agg_all + 1 * (size_t)NNODE * DF;
    __half* aggh_rg = agg_all + 2 * (size_t)NNODE * DF;
    __half* aggh_rr = agg_all + 3 * (size_t)NNODE * DF;
    uint2* bk_all = (uint2*)agg_all;

    __half* xh_gen  = (__half*)alloc((size_t)NNODE * DF * sizeof(__half));
    __half* xh_rain = (__half*)alloc((size_t)NNODE * DF * sizeof(__half));
    __half* WtH  = (__half*)alloc(4 * (size_t)128 * 256 * sizeof(__half));
    float*  bsum = (float*)alloc(4 * 128 * sizeof(float));

    int* rowptr[4]; unsigned int* ep[4]; uint2* bk[4];
    for (int r = 0; r < 4; ++r) {
        rowptr[r] = rowptr_all + (size_t)r * (NNODE + 1);
        ep[r]     = epack_all + (size_t)r * NES;
        bk[r]     = bk_all + (size_t)r * NE;
    }

    const int* rows_[4] = {ei[0], ei[1], ei[2], ei[3]};
    const int* cols_[4] = {ei[0] + NE, ei[1] + NE, ei[2] + NE, ei[3] + NE};

    prepW_k<<<dim3(128, 4), 256, 0, stream>>>(W_conv, b_conv, WtH, bsum);

    Pass1P PA;
    for (int r = 0; r < 4; ++r) PA.col[r] = cols_[r];
    PA.cnt1 = cnt1;
    PA.idx[0] = rows_[1]; PA.wgt[0] = w[1];
    PA.idx[1] = rows_[2]; PA.wgt[1] = w[2];
    PA.part = part_all;
    pass1_k<<<dim3(NCH, 6), 256, 0, stream>>>(PA);

    scan1_k<<<4, 128, 0, stream>>>(cnt1, bktbase);

    P1P P1;
    for (int r = 0; r < 4; ++r) {
        P1.row[r] = rows_[r]; P1.col[r] = cols_[r]; P1.w[r] = w[r]; P1.bk[r] = bk[r];
    }
    P1.choff = cnt1;
    P1.bktbase = bktbase;
    part1_k<<<dim3(NCH, 4), 256, 0, stream>>>(P1);

    Pass2P PB;
    PB.bk[0] = bk[0]; PB.bb[0] = bktbase + 0 * (NBKT + 1); PB.dinvD[0] = dinv_gg;
    PB.bk[1] = bk[3]; PB.bb[1] = bktbase + 3 * (NBKT + 1); PB.dinvD[1] = dinv_rr;
    PB.part = part_all;
    PB.dinvS[0] = dinv_gr_s;
    PB.dinvS[1] = dinv_rg_s;
    pass2_k<<<dim3(NBKT, 4), 256, 0, stream>>>(PB);

    P2P P2;
    for (int r = 0; r < 4; ++r) { P2.bk[r] = bk[r]; P2.rowptr[r] = rowptr[r]; P2.ep[r] = ep[r]; }
    P2.bktbase = bktbase;
    P2.dS[0] = dinv_gg;   P2.dDg[0] = dinv_gg;   P2.self[0] = 1;
    P2.dS[1] = dinv_gr_s; P2.dDg[1] = nullptr;   P2.self[1] = 0;
    P2.dS[2] = dinv_rg_s; P2.dDg[2] = nullptr;   P2.self[2] = 0;
    P2.dS[3] = dinv_rr;   P2.dDg[3] = dinv_rr;   P2.self[3] = 1;
    part2_k<<<dim3(NBKT, 4), 256, 0, stream>>>(P2);

    CvtP CV;
    CV.in[0] = x_gen;  CV.out[0] = xh_gen;
    CV.in[1] = x_rain; CV.out[1] = xh_rain;
    cvt_k<<<dim3(NNODE * DF / 4 / 256, 2), 256, 0, stream>>>(CV);

    for (int l = 0; l < 2; ++l) {
        SpmmP SP;
        for (int r = 0; r < 4; ++r) { SP.rowptr[r] = rowptr[r]; SP.ep[r] = ep[r]; }
        SP.x[0] = xh_gen; SP.x[1] = xh_gen; SP.x[2] = xh_rain; SP.x[3] = xh_rain;
        SP.out[0] = aggh_gg; SP.out[1] = aggh_gr; SP.out[2] = aggh_rg; SP.out[3] = aggh_rr;
        spmm4_k<<<20000, 256, 0, stream>>>(SP);

        Gemm2P GP;
        GP.A1[0] = aggh_gg; GP.A2[0] = aggh_rg;
        GP.A1[1] = aggh_gr; GP.A2[1] = aggh_rr;
        GP.Wt[0] = WtH + (size_t)(l * 2 + 0) * 128 * 256;
        GP.Wt[1] = WtH + (size_t)(l * 2 + 1) * 128 * 256;
        GP.bs[0] = bsum + (l * 2 + 0) * 128;
        GP.bs[1] = bsum + (l * 2 + 1) * 128;
        GP.out[0] = xh_gen;
        GP.out[1] = xh_rain;
        GP.Wh[0] = W_lg; GP.bh[0] = b_lg; GP.out16[0] = out_gen;
        GP.Wh[1] = W_lr; GP.bh[1] = b_lr; GP.out16[1] = out_rain;
        GP.last = (l == 1);
        gemm2_k<<<dim3(ceil_div(NNODE, 64), 2), 256, 0, stream>>>(GP);
    }
}

// Round 20
// 243.033 us; speedup vs baseline: 1.2310x; 1.0048x over previous
//
#include <hip/hip_runtime.h>
#include <hip/hip_fp16.h>

#define NNODE 20000
#define NE    600000
#define NES   (NE + NNODE)   // ep stride incl. self slots (used by gg, rr)
#define DF    128
#define DOUT  16
#define NBKT  80          // dst buckets
#define RNG   250         // nodes per bucket (80*250 = 20000 exact)
#define NCH   128         // partition chunks
#define CHE   4688        // edges per chunk (128*4688 >= NE)
#define BSTRIDE 8192      // fixed bk stride per bucket (mean 7500 + 8 sigma)
#define P2CAP 12288       // part2 staging capacity
#define SB2   64          // degree chunks per stream
#define CS2   (NE/SB2)    // 9375

typedef _Float16 f16x8 __attribute__((ext_vector_type(8)));
typedef _Float16 f16x2 __attribute__((ext_vector_type(2)));
typedef float f32x4 __attribute__((ext_vector_type(4)));

static inline int ceil_div(int a, int b) { return (a + b - 1) / b; }

// ---------------- fp32 -> fp16 conversion ----------------
struct CvtP { const float* in[2]; __half* out[2]; };
__global__ __launch_bounds__(256) void cvt_k(CvtP P) {
    int g = blockIdx.y;
    int i = blockIdx.x * 256 + threadIdx.x;
    const float4* in = (const float4*)P.in[g];
    __half2* out = (__half2*)P.out[g];
    float4 v = in[i];
    out[2 * i + 0] = __floats2half2_rn(v.x, v.y);
    out[2 * i + 1] = __floats2half2_rn(v.z, v.w);
}

// ---------------- W prep: combined, transposed, fp16 + folded bias ----------------
__global__ __launch_bounds__(256) void prepW_k(const float* __restrict__ W_conv,
                                               const float* __restrict__ b_conv,
                                               __half* __restrict__ WtH,
                                               float* __restrict__ bsum) {
    int lg = blockIdx.y;
    int l = lg >> 1, g = lg & 1;
    int ra = (g == 0) ? 0 : 1;
    int rb = (g == 0) ? 2 : 3;
    int idx = blockIdx.x * 256 + threadIdx.x;
    int col = idx >> 8, k = idx & 255;
    const float* Wa = W_conv + (size_t)(l * 4 + ra) * 128 * 128;
    const float* Wb = W_conv + (size_t)(l * 4 + rb) * 128 * 128;
    float v = (k < 128) ? Wa[k * 128 + col] : Wb[(k - 128) * 128 + col];
    WtH[((size_t)lg * 128 + col) * 256 + k] = __float2half(v);
    if (idx < 128)
        bsum[lg * 128 + idx] = 0.5f * (b_conv[(l * 4 + ra) * 128 + idx] +
                                       b_conv[(l * 4 + rb) * 128 + idx]);
}

// ---------------- src-degree partials (gr row, rg row) via LDS ----------------
struct DegPP { const int* idx[2]; const float* wgt[2]; float* part; };
__global__ __launch_bounds__(256) void degpart_k(DegPP P) {
    __shared__ float t[NNODE / 2];
    int s = blockIdx.y;
    int chunk = blockIdx.x >> 1, half = blockIdx.x & 1;
    int nbase = half * (NNODE / 2);
    for (int i = threadIdx.x; i < NNODE / 2; i += 256) t[i] = 0.f;
    __syncthreads();
    const int* idx = P.idx[s];
    const float* w = P.wgt[s];
    int e0 = chunk * CS2, e1 = min(NE, e0 + CS2);
    for (int e = e0 + threadIdx.x; e < e1; e += 256) {
        int rr = idx[e] - nbase;
        if ((unsigned)rr < (unsigned)(NNODE / 2)) atomicAdd(&t[rr], w[e]);
    }
    __syncthreads();
    float* pp = P.part + ((size_t)s * SB2 + chunk) * NNODE + nbase;
    for (int i = threadIdx.x; i < NNODE / 2; i += 256) pp[i] = t[i];
}

// ---------------- part1: LDS sort + atomic bucket-cursor flush (no count pass) ----------------
struct P1P {
    const int* row[4]; const int* col[4]; const float* w[4];
    int* bkcur;          // [4][NBKT] atomic cursors (pre-zeroed)
    uint2* bk[4];        // fixed-stride bucket storage (BSTRIDE records per bucket)
};
__global__ __launch_bounds__(256) void part1_k(P1P P) {
    __shared__ uint2 st[CHE];
    __shared__ int h[NBKT];
    __shared__ int hoff[NBKT];
    __shared__ int c2[NBKT];
    __shared__ int gbase[NBKT];
    __shared__ int sc[128];
    int ch = blockIdx.x, r = blockIdx.y;
    for (int i = threadIdx.x; i < NBKT; i += 256) { h[i] = 0; c2[i] = 0; }
    __syncthreads();
    const int* col = P.col[r];
    const int* row = P.row[r];
    const float* w = P.w[r];
    int e0 = ch * CHE, e1 = min(NE, e0 + CHE);
    for (int e = e0 + threadIdx.x; e < e1; e += 256) atomicAdd(&h[col[e] / RNG], 1);
    __syncthreads();
    int v = 0;
    if (threadIdx.x < 128) {
        v = (threadIdx.x < NBKT) ? h[threadIdx.x] : 0;
        sc[threadIdx.x] = v;
    }
    __syncthreads();
    for (int o = 1; o < 128; o <<= 1) {
        int add = 0;
        if (threadIdx.x < 128 && threadIdx.x >= o) add = sc[threadIdx.x - o];
        __syncthreads();
        if (threadIdx.x < 128) sc[threadIdx.x] += add;
        __syncthreads();
    }
    if (threadIdx.x < NBKT) {
        hoff[threadIdx.x] = sc[threadIdx.x] - v;
        gbase[threadIdx.x] = atomicAdd(&P.bkcur[r * NBKT + threadIdx.x], v);
    }
    __syncthreads();
    for (int e = e0 + threadIdx.x; e < e1; e += 256) {
        int c = col[e];
        int b = c / RNG;
        int slot = hoff[b] + atomicAdd(&c2[b], 1);
        uint2 rec;
        rec.x = ((unsigned)c << 15) | (unsigned)row[e];
        rec.y = (unsigned)__float_as_int(w[e]);
        st[slot] = rec;
    }
    __syncthreads();
    uint2* bk = P.bk[r];
    for (int b = 0; b < NBKT; ++b) {
        int m = h[b];
        if (m == 0) continue;
        int base = b * BSTRIDE + gbase[b];
        int lo = hoff[b];
        for (int i = threadIdx.x; i < m; i += 256) bk[base + i] = st[lo + i];
    }
}

// ---------------- miniscan: contiguous ep bases from bucket counts (1 tiny block) ----------------
__global__ void miniscan_k(const int* __restrict__ bkcur, int* __restrict__ bktbase) {
    int r = threadIdx.x;
    if (r < 4) {
        int run = 0;
        int* bb = bktbase + r * (NBKT + 1);
        const int* bc = bkcur + r * NBKT;
        for (int b = 0; b < NBKT; ++b) { bb[b] = run; run += bc[b]; }
        bb[NBKT] = run;
    }
}

// ---------------- pass2: gg/rr dst degrees from bk (y 0..1) + src-degree reduce (y 2..3) ----------------
struct Pass2P {
    const uint2* bk[2]; const int* bkcnt[2]; float* dinvD[2];
    const float* part; float* dinvS[2];
};
__global__ __launch_bounds__(256) void pass2_k(Pass2P P) {
    __shared__ float t[RNG];
    int y = blockIdx.y;
    if (y < 2) {
        int bkt = blockIdx.x, r2 = y;
        for (int i = threadIdx.x; i < RNG; i += 256) t[i] = 0.f;
        __syncthreads();
        int b0 = bkt * BSTRIDE;
        int n = P.bkcnt[r2][bkt];
        const uint2* bk = P.bk[r2];
        int nlo = bkt * RNG;
        for (int i = threadIdx.x; i < n; i += 256) {
            uint2 rec = bk[b0 + i];
            atomicAdd(&t[(int)(rec.x >> 15) - nlo], __int_as_float((int)rec.y));
        }
        __syncthreads();
        float* dv = P.dinvD[r2];
        for (int c = threadIdx.x; c < RNG; c += 256) dv[nlo + c] = rsqrtf(t[c] + 1.0f);
    } else {
        int s = y - 2;
        int n = blockIdx.x * 256 + threadIdx.x;
        if (n >= NNODE) return;
        const float* pp = P.part + (size_t)s * SB2 * NNODE + n;
        float acc = 0.f;
        for (int c = 0; c < SB2; ++c) acc += pp[(size_t)c * NNODE];
        P.dinvS[s][n] = acc > 0.f ? rsqrtf(acc) : 0.f;
    }
}

// ---------------- part2: bucket -> CSR segment (parallel 256-slot scan) ----------------
struct P2P {
    const uint2* bk[4];
    const int* bkcur;       // [4][NBKT] bucket counts
    const int* bktbase;     // [4][NBKT+1] contiguous ep bases
    const float* dS[4];
    const float* dDg[4];
    int self[4];
    int* rowptr[4];
    unsigned int* ep[4];
};
__global__ __launch_bounds__(256) void part2_k(P2P P) {
    __shared__ unsigned int st[P2CAP];
    __shared__ float wsum[RNG];
    __shared__ int cnt[RNG];
    __shared__ int off[RNG + 1];
    __shared__ int cur[RNG];
    __shared__ int sc[256];
    int bkt = blockIdx.x, r = blockIdx.y;
    int selfF = P.self[r];
    int b0 = bkt * BSTRIDE;
    int n = P.bkcur[r * NBKT + bkt];
    const int* bb = P.bktbase + r * (NBKT + 1);
    for (int i = threadIdx.x; i < RNG; i += 256) { wsum[i] = 0.f; cnt[i] = 0; cur[i] = 0; }
    __syncthreads();
    const uint2* bk = P.bk[r];
    int nlo = bkt * RNG;
    for (int i = threadIdx.x; i < n; i += 256) {
        uint2 rec = bk[b0 + i];
        int cl = (int)(rec.x >> 15) - nlo;
        atomicAdd(&cnt[cl], 1);
        if (!selfF) atomicAdd(&wsum[cl], __int_as_float((int)rec.y));
    }
    __syncthreads();
    int v = (threadIdx.x < RNG) ? cnt[threadIdx.x] + selfF : 0;
    sc[threadIdx.x] = v;
    __syncthreads();
    for (int o = 1; o < 256; o <<= 1) {
        int add = (threadIdx.x >= o) ? sc[threadIdx.x - o] : 0;
        __syncthreads();
        sc[threadIdx.x] += add;
        __syncthreads();
    }
    if (threadIdx.x < RNG) off[threadIdx.x] = sc[threadIdx.x] - v;
    if (threadIdx.x == 255) off[RNG] = sc[255];
    __syncthreads();
    int ntot = off[RNG];
    int epseg = bb[bkt] + (selfF ? nlo : 0);
    int* rp = P.rowptr[r];
    for (int c = threadIdx.x; c < RNG; c += 256) rp[nlo + c] = epseg + off[c];
    if (bkt == NBKT - 1 && threadIdx.x == 0) rp[NNODE] = epseg + ntot;
    const float* dDg = P.dDg[r];
    if (!selfF) {
        for (int c = threadIdx.x; c < RNG; c += 256) {
            float s = wsum[c];
            wsum[c] = s > 0.f ? rsqrtf(s) : 0.f;
        }
    }
    __syncthreads();
    if (selfF) {
        for (int c = threadIdx.x; c < RNG; c += 256) {
            float d = dDg[nlo + c];
            __half hh = __float2half(d * d);
            st[off[c]] = ((unsigned)(nlo + c) << 16) | *reinterpret_cast<unsigned short*>(&hh);
        }
    }
    const float* dS = P.dS[r];
    for (int i = threadIdx.x; i < n; i += 256) {
        uint2 rec = bk[b0 + i];
        int cg = (int)(rec.x >> 15);
        int cl = cg - nlo;
        int src = (int)(rec.x & 0x7fffu);
        float w = __int_as_float((int)rec.y);
        float dD = selfF ? dDg[cg] : wsum[cl];
        float nm = dS[src] * w * dD;
        int slot = off[cl] + selfF + atomicAdd(&cur[cl], 1);
        __half hh = __float2half(nm);
        st[slot] = ((unsigned)src << 16) | *reinterpret_cast<unsigned short*>(&hh);
    }
    __syncthreads();
    unsigned int* ep = P.ep[r];
    int eb = bb[bkt] + selfF * nlo;
    for (int i = threadIdx.x; i < ntot; i += 256) ep[eb + i] = st[i];
}

// ---------------- pull-SpMM: quarter-wave gather, dot2 pairs (R12 proven form) ----------------
struct SpmmP {
    const __half* x[4]; const int* rowptr[4]; const unsigned int* ep[4]; __half* out[4];
};
__global__ __launch_bounds__(256) void spmm4_k(SpmmP P) {
    int b = blockIdx.x;
    int xcd = b & 7;
    int j = b >> 3;
    int r = ((xcd >> 2) << 1) + (j >= 1250 ? 1 : 0);
    int nodeblk = (xcd & 3) * 1250 + (j >= 1250 ? j - 1250 : j);
    int wid = nodeblk * 4 + (threadIdx.x >> 6);
    int lane = threadIdx.x & 63;
    int q = lane >> 4, c = lane & 15;
    const uint4* x4 = (const uint4*)P.x[r];
    const int* rp = P.rowptr[r];
    int bb = rp[wid], ee = rp[wid + 1];
    const unsigned int* ep = P.ep[r];
    float a[8];
#pragma unroll
    for (int t = 0; t < 8; ++t) a[t] = 0.f;

    auto decn = [](unsigned int v) -> float {
        unsigned short us = (unsigned short)(v & 0xffffu);
        __half h = *reinterpret_cast<__half*>(&us);
        return __half2float(h);
    };
    auto accum1 = [&](uint4 p, float n) {
        const __half2* ph = (const __half2*)&p;
#pragma unroll
        for (int t = 0; t < 4; ++t) {
            float2 f = __half22float2(ph[t]);
            a[2 * t]     = fmaf(f.x, n, a[2 * t]);
            a[2 * t + 1] = fmaf(f.y, n, a[2 * t + 1]);
        }
    };
    auto accum2 = [&](uint4 p0, uint4 p1, unsigned n01) {
        f16x2 nn = __builtin_bit_cast(f16x2, n01);
        const unsigned* u0 = (const unsigned*)&p0;
        const unsigned* u1 = (const unsigned*)&p1;
#pragma unroll
        for (int t = 0; t < 4; ++t) {
            unsigned plo = __builtin_amdgcn_perm(u1[t], u0[t], 0x05040100u);
            unsigned phi = __builtin_amdgcn_perm(u1[t], u0[t], 0x07060302u);
            a[2 * t]     = __builtin_amdgcn_fdot2(__builtin_bit_cast(f16x2, plo), nn, a[2 * t], false);
            a[2 * t + 1] = __builtin_amdgcn_fdot2(__builtin_bit_cast(f16x2, phi), nn, a[2 * t + 1], false);
        }
    };

    int i = bb + q;
    for (; i + 12 < ee; i += 16) {
        unsigned v0 = ep[i], v1 = ep[i + 4], v2 = ep[i + 8], v3 = ep[i + 12];
        uint4 p0 = x4[(size_t)(v0 >> 16) * 16 + c];
        uint4 p1 = x4[(size_t)(v1 >> 16) * 16 + c];
        uint4 p2 = x4[(size_t)(v2 >> 16) * 16 + c];
        uint4 p3 = x4[(size_t)(v3 >> 16) * 16 + c];
        accum2(p0, p1, __builtin_amdgcn_perm(v1, v0, 0x05040100u));
        accum2(p2, p3, __builtin_amdgcn_perm(v3, v2, 0x05040100u));
    }
    for (; i + 4 < ee; i += 8) {
        unsigned v0 = ep[i], v1 = ep[i + 4];
        uint4 p0 = x4[(size_t)(v0 >> 16) * 16 + c];
        uint4 p1 = x4[(size_t)(v1 >> 16) * 16 + c];
        accum2(p0, p1, __builtin_amdgcn_perm(v1, v0, 0x05040100u));
    }
    if (i < ee) {
        unsigned v0 = ep[i];
        uint4 p0 = x4[(size_t)(v0 >> 16) * 16 + c];
        accum1(p0, decn(v0));
    }
#pragma unroll
    for (int t = 0; t < 8; ++t) {
        a[t] += __shfl_xor(a[t], 16, 64);
        a[t] += __shfl_xor(a[t], 32, 64);
    }
    if (q == 0) {
        __half2 h[4];
#pragma unroll
        for (int t = 0; t < 4; ++t) h[t] = __floats2half2_rn(a[2 * t], a[2 * t + 1]);
        ((uint4*)P.out[r])[(size_t)wid * 16 + c] = *(uint4*)h;
    }
}

// ---------------- MFMA gemm2 (+ fused 128->16 head on the last layer) ----------------
struct Gemm2P {
    const __half* A1[2]; const __half* A2[2];
    const __half* Wt[2];
    const float* bs[2];
    __half* out[2];
    const float* Wh[2];
    const float* bh[2];
    float* out16[2];
    int last;
};
__global__ __launch_bounds__(256) void gemm2_k(Gemm2P P) {
    __shared__ __half sW[128 * 136];
    int g = blockIdx.y;
    int w = threadIdx.x >> 6, l = threadIdx.x & 63;
    int r0 = blockIdx.x * 64 + w * 16;
    int lm = l & 15, lh = l >> 4;
    f32x4 acc[8];
    f32x4 zero = {0.f, 0.f, 0.f, 0.f};
#pragma unroll
    for (int n = 0; n < 8; ++n) acc[n] = zero;
    const __half* As[2] = { P.A1[g], P.A2[g] };
    const uint4* wg = (const uint4*)P.Wt[g];
    int arow = r0 + lm;
    bool rok = arow < NNODE;
    for (int s = 0; s < 2; ++s) {
        __syncthreads();
        for (int u = threadIdx.x; u < 2048; u += 256) {
            int col = u >> 4, kb8 = u & 15;
            uint4 vv = wg[col * 32 + s * 16 + kb8];
            *(uint4*)&sW[col * 136 + kb8 * 8] = vv;
        }
        __syncthreads();
        const uint4* a4 = (const uint4*)As[s];
#pragma unroll
        for (int kk = 0; kk < 4; ++kk) {
            uint4 av = make_uint4(0, 0, 0, 0);
            if (rok) av = a4[(size_t)arow * 16 + kk * 4 + lh];
            f16x8 af = *(f16x8*)&av;
#pragma unroll
            for (int n = 0; n < 8; ++n) {
                uint4 bv = *(uint4*)&sW[(n * 16 + lm) * 136 + kk * 32 + lh * 8];
                f16x8 bf = *(f16x8*)&bv;
                acc[n] = __builtin_amdgcn_mfma_f32_16x16x32_f16(af, bf, acc[n], 0, 0, 0);
            }
        }
    }
    const float* bs = P.bs[g];
    if (!P.last) {
        __half* out = P.out[g];
#pragma unroll
        for (int n = 0; n < 8; ++n) {
            int colg = n * 16 + lm;
            float bb = bs[colg];
#pragma unroll
            for (int qq = 0; qq < 4; ++qq) {
                int rowg = r0 + lh * 4 + qq;
                if (rowg < NNODE) {
                    float v = fmaf(acc[n][qq], 0.5f, bb);
                    out[(size_t)rowg * 128 + colg] = __float2half(v > 0.f ? v : 0.f);
                }
            }
        }
    } else {
        __syncthreads();
        __half* tile = sW + (size_t)w * 16 * 136;
#pragma unroll
        for (int n = 0; n < 8; ++n) {
            int colg = n * 16 + lm;
            float bb = bs[colg];
#pragma unroll
            for (int qq = 0; qq < 4; ++qq) {
                int rowl = lh * 4 + qq;
                float v = fmaf(acc[n][qq], 0.5f, bb);
                tile[rowl * 136 + colg] = __float2half(v > 0.f ? v : 0.f);
            }
        }
        const float* Wh = P.Wh[g];
        const float* bh = P.bh[g];
        int row = l & 15, grp = l >> 4;
        int rowg = r0 + row;
        float a4[4];
#pragma unroll
        for (int c = 0; c < 4; ++c) a4[c] = bh[grp * 4 + c];
        for (int k = 0; k < 128; ++k) {
            float tv = __half2float(tile[row * 136 + k]);
#pragma unroll
            for (int c = 0; c < 4; ++c) a4[c] = fmaf(tv, Wh[k * 16 + grp * 4 + c], a4[c]);
        }
        if (rowg < NNODE) {
            float4 vv = make_float4(a4[0], a4[1], a4[2], a4[3]);
            *(float4*)&P.out16[g][(size_t)rowg * 16 + grp * 4] = vv;
        }
    }
}

extern "C" void kernel_launch(void* const* d_in, const int* in_sizes, int n_in,
                              void* d_out, int out_size, void* d_ws, size_t ws_size,
                              hipStream_t stream) {
    (void)in_sizes; (void)n_in; (void)out_size; (void)ws_size;

    const float* x_gen  = (const float*)d_in[0];
    const float* x_rain = (const float*)d_in[1];
    const int* ei[4] = {(const int*)d_in[2], (const int*)d_in[3], (const int*)d_in[4], (const int*)d_in[5]};
    const float* w[4] = {(const float*)d_in[6], (const float*)d_in[7], (const float*)d_in[8], (const float*)d_in[9]};
    const float* W_conv = (const float*)d_in[10];
    const float* b_conv = (const float*)d_in[11];
    const float* W_lg = (const float*)d_in[12];
    const float* b_lg = (const float*)d_in[13];
    const float* W_lr = (const float*)d_in[14];
    const float* b_lr = (const float*)d_in[15];

    float* out_gen  = (float*)d_out;
    float* out_rain = out_gen + (size_t)NNODE * DOUT;

    char* p = (char*)d_ws;
    auto alloc = [&](size_t bytes) -> void* {
        void* r = (void*)p;
        p += (bytes + 255) & ~(size_t)255;
        return r;
    };

    float* deg = (float*)alloc(4 * (size_t)NNODE * sizeof(float));
    float* dinv_gg   = deg + 0 * NNODE;
    float* dinv_rr   = deg + 1 * NNODE;
    float* dinv_gr_s = deg + 2 * NNODE;
    float* dinv_rg_s = deg + 3 * NNODE;

    int* rowptr_all = (int*)alloc(4 * (size_t)(NNODE + 1) * sizeof(int));
    int* bkcur      = (int*)alloc(4 * (size_t)NBKT * sizeof(int));
    int* bktbase    = (int*)alloc(4 * (size_t)(NBKT + 1) * sizeof(int));

    size_t epack_bytes = 4 * (size_t)NES * sizeof(unsigned int);
    size_t part_bytes  = 2 * (size_t)SB2 * NNODE * sizeof(float);
    unsigned int* epack_all = (unsigned int*)alloc(epack_bytes > part_bytes ? epack_bytes : part_bytes);
    float* part_all = (float*)epack_all;

    __half* agg_all = (__half*)alloc(4 * (size_t)NNODE * DF * sizeof(__half));
    __half* aggh_gg = agg_all + 0 * (size_t)NNODE * DF;
    __half* aggh_gr = agg_all + 1 * (size_t)NNODE * DF;
    __half* aggh_rg = agg_all + 2 * (size_t)NNODE * DF;
    __half* aggh_rr = agg_all + 3 * (size_t)NNODE * DF;

    uint2* bk_all = (uint2*)alloc(4 * (size_t)NBKT * BSTRIDE * sizeof(uint2));  // 21 MB

    __half* xh_gen  = (__half*)alloc((size_t)NNODE * DF * sizeof(__half));
    __half* xh_rain = (__half*)alloc((size_t)NNODE * DF * sizeof(__half));
    __half* WtH  = (__half*)alloc(4 * (size_t)128 * 256 * sizeof(__half));
    float*  bsum = (float*)alloc(4 * 128 * sizeof(float));

    int* rowptr[4]; unsigned int* ep[4]; uint2* bk[4];
    for (int r = 0; r < 4; ++r) {
        rowptr[r] = rowptr_all + (size_t)r * (NNODE + 1);
        ep[r]     = epack_all + (size_t)r * NES;
        bk[r]     = bk_all + (size_t)r * NBKT * BSTRIDE;
    }

    const int* rows_[4] = {ei[0], ei[1], ei[2], ei[3]};
    const int* cols_[4] = {ei[0] + NE, ei[1] + NE, ei[2] + NE, ei[3] + NE};

    prepW_k<<<dim3(128, 4), 256, 0, stream>>>(W_conv, b_conv, WtH, bsum);

    hipMemsetAsync(bkcur, 0, 4 * NBKT * sizeof(int), stream);

    DegPP DP;
    DP.idx[0] = rows_[1]; DP.wgt[0] = w[1];
    DP.idx[1] = rows_[2]; DP.wgt[1] = w[2];
    DP.part = part_all;
    degpart_k<<<dim3(SB2 * 2, 2), 256, 0, stream>>>(DP);

    P1P P1;
    for (int r = 0; r < 4; ++r) {
        P1.row[r] = rows_[r]; P1.col[r] = cols_[r]; P1.w[r] = w[r]; P1.bk[r] = bk[r];
    }
    P1.bkcur = bkcur;
    part1_k<<<dim3(NCH, 4), 256, 0, stream>>>(P1);

    miniscan_k<<<1, 64, 0, stream>>>(bkcur, bktbase);

    Pass2P PB;
    PB.bk[0] = bk[0]; PB.bkcnt[0] = bkcur + 0 * NBKT; PB.dinvD[0] = dinv_gg;
    PB.bk[1] = bk[3]; PB.bkcnt[1] = bkcur + 3 * NBKT; PB.dinvD[1] = dinv_rr;
    PB.part = part_all;
    PB.dinvS[0] = dinv_gr_s;
    PB.dinvS[1] = dinv_rg_s;
    pass2_k<<<dim3(NBKT, 4), 256, 0, stream>>>(PB);

    P2P P2;
    for (int r = 0; r < 4; ++r) { P2.bk[r] = bk[r]; P2.rowptr[r] = rowptr[r]; P2.ep[r] = ep[r]; }
    P2.bkcur = bkcur;
    P2.bktbase = bktbase;
    P2.dS[0] = dinv_gg;   P2.dDg[0] = dinv_gg;   P2.self[0] = 1;
    P2.dS[1] = dinv_gr_s; P2.dDg[1] = nullptr;   P2.self[1] = 0;
    P2.dS[2] = dinv_rg_s; P2.dDg[2] = nullptr;   P2.self[2] = 0;
    P2.dS[3] = dinv_rr;   P2.dDg[3] = dinv_rr;   P2.self[3] = 1;
    part2_k<<<dim3(NBKT, 4), 256, 0, stream>>>(P2);

    CvtP CV;
    CV.in[0] = x_gen;  CV.out[0] = xh_gen;
    CV.in[1] = x_rain; CV.out[1] = xh_rain;
    cvt_k<<<dim3(NNODE * DF / 4 / 256, 2), 256, 0, stream>>>(CV);

    for (int l = 0; l < 2; ++l) {
        SpmmP SP;
        for (int r = 0; r < 4; ++r) { SP.rowptr[r] = rowptr[r]; SP.ep[r] = ep[r]; }
        SP.x[0] = xh_gen; SP.x[1] = xh_gen; SP.x[2] = xh_rain; SP.x[3] = xh_rain;
        SP.out[0] = aggh_gg; SP.out[1] = aggh_gr; SP.out[2] = aggh_rg; SP.out[3] = aggh_rr;
        spmm4_k<<<20000, 256, 0, stream>>>(SP);

        Gemm2P GP;
        GP.A1[0] = aggh_gg; GP.A2[0] = aggh_rg;
        GP.A1[1] = aggh_gr; GP.A2[1] = aggh_rr;
        GP.Wt[0] = WtH + (size_t)(l * 2 + 0) * 128 * 256;
        GP.Wt[1] = WtH + (size_t)(l * 2 + 1) * 128 * 256;
        GP.bs[0] = bsum + (l * 2 + 0) * 128;
        GP.bs[1] = bsum + (l * 2 + 1) * 128;
        GP.out[0] = xh_gen;
        GP.out[1] = xh_rain;
        GP.Wh[0] = W_lg; GP.bh[0] = b_lg; GP.out16[0] = out_gen;
        GP.Wh[1] = W_lr; GP.bh[1] = b_lr; GP.out16[1] = out_rain;
        GP.last = (l == 1);
        gemm2_k<<<dim3(ceil_div(NNODE, 64), 2), 256, 0, stream>>>(GP);
    }
}